// Round 16
// baseline (2794.690 us; speedup 1.0000x reference)
//
#include <hip/hip_runtime.h>
#include <hip/hip_cooperative_groups.h>
#include <math.h>

namespace cg = cooperative_groups;

#define Bn 32
#define Sn 512
#define Hn 1024
#define Tn 8
#define Nn 16
#define Gn 4096

__device__ __forceinline__ float wsum(float v){
#pragma unroll
  for (int off = 32; off; off >>= 1) v += __shfl_xor(v, off);
  return v;
}

__device__ __forceinline__ float dot16(float4 a0, float4 a1, float4 a2, float4 a3,
                                       float4 v0, float4 v1, float4 v2, float4 v3){
  float d = a0.x*v0.x + a0.y*v0.y + a0.z*v0.z + a0.w*v0.w;
  d += a1.x*v1.x + a1.y*v1.y + a1.z*v1.z + a1.w*v1.w;
  d += a2.x*v2.x + a2.y*v2.y + a2.z*v2.z + a2.w*v2.w;
  d += a3.x*v3.x + a3.y*v3.y + a3.z*v3.z + a3.w*v3.w;
  return d;
}

// ---------------- prep: 3 transposes + nums/pq copies in ONE launch ----------
__global__ __launch_bounds__(256) void transprep(
    const float* __restrict__ Wk, const float* __restrict__ Wk2, const float* __restrict__ Wv,
    float* __restrict__ WkT, float* __restrict__ Wk2T, float* __restrict__ WvT,
    const float4* __restrict__ nums, const float4* __restrict__ pq,
    float4* __restrict__ un, float4* __restrict__ xs){
  if (blockIdx.z == 3){
    int n = blockIdx.x, b = blockIdx.y;
    if (n < Nn) un[((size_t)b*(Nn+Tn) + n)*256 + threadIdx.x] = nums[((size_t)b*Nn + n)*256 + threadIdx.x];
    else if (n == Nn) xs[((size_t)b*Tn)*256 + threadIdx.x] = pq[(size_t)b*256 + threadIdx.x];
    return;
  }
  __shared__ float tile[32][33];
  const float* in  = (blockIdx.z == 0) ? Wk  : (blockIdx.z == 1) ? Wk2  : Wv;
  float*       outp= (blockIdx.z == 0) ? WkT : (blockIdx.z == 1) ? Wk2T : WvT;
  int tx = threadIdx.x & 31, ty = threadIdx.x >> 5;
  int c0 = blockIdx.x * 32, r0 = blockIdx.y * 32;
#pragma unroll
  for (int k = 0; k < 4; ++k)
    tile[ty + 8*k][tx] = in[(size_t)(r0 + ty + 8*k) * Hn + c0 + tx];
  __syncthreads();
#pragma unroll
  for (int k = 0; k < 4; ++k)
    outp[(size_t)(c0 + ty + 8*k) * Hn + r0 + tx] = tile[tx][ty + 8*k];
}

__global__ __launch_bounds__(256) void finalize_xs(const float4* __restrict__ xs, float4* __restrict__ uh, float4* __restrict__ un){
  int t = blockIdx.x, b = blockIdx.y;
  float4 v = xs[((size_t)b*Tn + t)*256 + threadIdx.x];
  uh[(((size_t)(Sn + t))*Bn + b)*256 + threadIdx.x] = v;
  un[((size_t)b*(Nn+Tn) + Nn + t)*256 + threadIdx.x] = v;
}

// ---------------- dred: Dcomb split-K reduce + dkv fused. grid 4352 ----------
__global__ __launch_bounds__(256) void dred(
    const float* __restrict__ Dparts, float* __restrict__ Dcomb,
    const float* __restrict__ bv, const float* __restrict__ WkT, float* __restrict__ dk)
{
  if (blockIdx.x < 4096){
    int idx = blockIdx.x*256 + threadIdx.x;
    const size_t stride = (size_t)1024*1024;
    float s = Dparts[idx] + Dparts[stride + idx] + Dparts[2*stride + idx] + Dparts[3*stride + idx];
    Dcomb[idx] = s;
  } else {
    int lane = threadIdx.x & 63, w = threadIdx.x >> 6;
    int j = (blockIdx.x - 4096)*4 + w;
    const float4* rp = (const float4*)(WkT + (size_t)j*Hn) + lane;
    const float4* bp = (const float4*)bv + lane;
    float4 v0=rp[0], v1=rp[64], v2=rp[128], v3=rp[192];
    float4 b0=bp[0], b1=bp[64], b2=bp[128], b3=bp[192];
    float d = wsum(dot16(b0,b1,b2,b3, v0,v1,v2,v3));
    if (lane == 0) dk[j] = d;
  }
}

// ---------------- cooperative persistent gen loop (24.6 KB LDS) ----------------
// 512 blocks x 512 threads, 2 blocks/CU even under a 64KB-LDS occupancy model.
// Block (p,b) holds its 32 hidden rows in registers across all 7 steps.
__global__ __launch_bounds__(512, 4) void coop_gen(
    const float* __restrict__ hidden, const float* __restrict__ partK,
    const float* __restrict__ dk, const float* __restrict__ D,
    float* __restrict__ partX, float* __restrict__ ctxp, float* __restrict__ mlp,
    float* __restrict__ ctxall, float* __restrict__ uh)
{
  cg::grid_group grid = cg::this_grid();
  __shared__ float smem[6160];   // attend: xq(1024)+sacc(4096)+sM(8)+sL(8); genw: xll(2048)+wtlh(4096)

  const int bid = blockIdx.x;
  const int p = bid & 15, b = bid >> 4;
  const int tid = threadIdx.x, lane = tid & 63, w = tid >> 6;

  const int s0 = p*32 + w*4;
  size_t ro[4];
#pragma unroll
  for (int i = 0; i < 4; ++i) ro[i] = ((size_t)(s0+i)*Bn + b)*Hn;
  float4 u[4][4];
#pragma unroll
  for (int i = 0; i < 4; ++i){
    const float4* rp = (const float4*)(hidden + ro[i]) + lane;
    u[i][0]=rp[0]; u[i][1]=rp[64]; u[i][2]=rp[128]; u[i][3]=rp[192];
  }
#pragma unroll
  for (int i = 0; i < 4; ++i){
    float4* wp = (float4*)(uh + ro[i]) + lane;
    wp[0]=u[i][0]; wp[64]=u[i][1]; wp[128]=u[i][2]; wp[192]=u[i][3];
  }

  for (int t = 1; t < Tn; ++t){
    // ---------- attend phase ----------
    {
      float* xq   = smem;
      float* sacc = smem + 1024;   // 4 regions x 1024
      float* sM   = smem + 5120;
      float* sL   = smem + 5128;
      const float* pq_ = (t == 1) ? partK : partX;
#pragma unroll
      for (int h0 = 0; h0 < 1024; h0 += 512){
        int c = h0 + tid;
        float s = (t != 1) ? dk[c] : 0.f;
#pragma unroll
        for (int i = 0; i < 16; ++i) s += pq_[((size_t)(i*Bn + b))*1024 + c];
        xq[c] = s;
      }
      __syncthreads();
      const float4* xp = (const float4*)xq + lane;
      float4 q0 = xp[0], q1 = xp[64], q2 = xp[128], q3 = xp[192];

      float d[4];
#pragma unroll
      for (int i = 0; i < 4; ++i) d[i] = dot16(q0,q1,q2,q3, u[i][0],u[i][1],u[i][2],u[i][3]);
#pragma unroll
      for (int off = 32; off; off >>= 1){
#pragma unroll
        for (int i = 0; i < 4; ++i) d[i] += __shfl_xor(d[i], off);
      }
      float mw = fmaxf(fmaxf(d[0], d[1]), fmaxf(d[2], d[3]));
      sM[w] = mw;
      __syncthreads();
      float M = sM[0];
#pragma unroll
      for (int i = 1; i < 8; ++i) M = fmaxf(M, sM[i]);
      float wi[4], lw = 0.f;
#pragma unroll
      for (int i = 0; i < 4; ++i){ wi[i] = __expf(d[i] - M); lw += wi[i]; }
      float4 a0, a1, a2, a3;
      a0 = make_float4(wi[0]*u[0][0].x, wi[0]*u[0][0].y, wi[0]*u[0][0].z, wi[0]*u[0][0].w);
      a1 = make_float4(wi[0]*u[0][1].x, wi[0]*u[0][1].y, wi[0]*u[0][1].z, wi[0]*u[0][1].w);
      a2 = make_float4(wi[0]*u[0][2].x, wi[0]*u[0][2].y, wi[0]*u[0][2].z, wi[0]*u[0][2].w);
      a3 = make_float4(wi[0]*u[0][3].x, wi[0]*u[0][3].y, wi[0]*u[0][3].z, wi[0]*u[0][3].w);
#pragma unroll
      for (int i = 1; i < 4; ++i){
        a0.x = fmaf(wi[i], u[i][0].x, a0.x); a0.y = fmaf(wi[i], u[i][0].y, a0.y);
        a0.z = fmaf(wi[i], u[i][0].z, a0.z); a0.w = fmaf(wi[i], u[i][0].w, a0.w);
        a1.x = fmaf(wi[i], u[i][1].x, a1.x); a1.y = fmaf(wi[i], u[i][1].y, a1.y);
        a1.z = fmaf(wi[i], u[i][1].z, a1.z); a1.w = fmaf(wi[i], u[i][1].w, a1.w);
        a2.x = fmaf(wi[i], u[i][2].x, a2.x); a2.y = fmaf(wi[i], u[i][2].y, a2.y);
        a2.z = fmaf(wi[i], u[i][2].z, a2.z); a2.w = fmaf(wi[i], u[i][2].w, a2.w);
        a3.x = fmaf(wi[i], u[i][3].x, a3.x); a3.y = fmaf(wi[i], u[i][3].y, a3.y);
        a3.z = fmaf(wi[i], u[i][3].z, a3.z); a3.w = fmaf(wi[i], u[i][3].w, a3.w);
      }
      int sl0 = (lane*4 + 0) ^ (lane & 7);
      int sl1 = (lane*4 + 1) ^ (lane & 7);
      int sl2 = (lane*4 + 2) ^ (lane & 7);
      int sl3 = (lane*4 + 3) ^ (lane & 7);
      if (w >= 4){
        float* rg = sacc + (w-4)*1024;
        *(float4*)(rg + sl0*4) = a0;
        *(float4*)(rg + sl1*4) = a1;
        *(float4*)(rg + sl2*4) = a2;
        *(float4*)(rg + sl3*4) = a3;
      }
      if (lane == 0) sL[w] = lw;
      __syncthreads();
      if (w < 4){
        float* rg = sacc + w*1024;
        float4 o0 = *(float4*)(rg + sl0*4);
        float4 o1 = *(float4*)(rg + sl1*4);
        float4 o2 = *(float4*)(rg + sl2*4);
        float4 o3 = *(float4*)(rg + sl3*4);
        a0.x+=o0.x; a0.y+=o0.y; a0.z+=o0.z; a0.w+=o0.w;
        a1.x+=o1.x; a1.y+=o1.y; a1.z+=o1.z; a1.w+=o1.w;
        a2.x+=o2.x; a2.y+=o2.y; a2.z+=o2.z; a2.w+=o2.w;
        a3.x+=o3.x; a3.y+=o3.y; a3.z+=o3.z; a3.w+=o3.w;
        *(float4*)(rg + sl0*4) = a0;
        *(float4*)(rg + sl1*4) = a1;
        *(float4*)(rg + sl2*4) = a2;
        *(float4*)(rg + sl3*4) = a3;
      }
      __syncthreads();
#pragma unroll
      for (int h0 = 0; h0 < 1024; h0 += 512){
        int c = h0 + tid;
        int k = c >> 8, l = (c >> 2) & 63, j = c & 3;
        int fo = ((((l << 2) + k) ^ (l & 7)) << 2) + j;
        float s = 0.f;
#pragma unroll
        for (int i = 0; i < 4; ++i) s += sacc[i*1024 + fo];
        ctxp[((size_t)b*16 + p)*1024 + c] = s;
      }
      if (tid == 0){
        float L = 0.f;
#pragma unroll
        for (int i = 0; i < 8; ++i) L += sL[i];
        mlp[((size_t)b*16 + p)*2]     = M;
        mlp[((size_t)b*16 + p)*2 + 1] = L;
      }
    }
    __threadfence();
    grid.sync();
    __threadfence();

    // ---------- genw phase ----------
    if (t < Tn-1){
      if (bid < 128){
        float* xll  = smem;          // 2048 (64k x 32b)
        float* wtlh = smem + 2048;   // 4096 (32k x 128j half-tile)
        const int j0 = (bid & 7) * 128;
        const int kb = bid >> 3;
        const int k0 = kb*64;
        {
          int bb = tid >> 4, kk = (tid & 15)*4;
          float mx = -1e30f;
#pragma unroll
          for (int i = 0; i < 16; ++i) mx = fmaxf(mx, mlp[((size_t)bb*16 + i)*2]);
          float L = 0.f;
          float a4[4] = {0.f,0.f,0.f,0.f};
#pragma unroll 4
          for (int i = 0; i < 16; ++i){
            float m = mlp[((size_t)bb*16 + i)*2];
            float l = mlp[((size_t)bb*16 + i)*2 + 1];
            float we = __expf(m - mx);
            L = fmaf(l, we, L);
            float4 uu = *(const float4*)(ctxp + ((size_t)bb*16 + i)*1024 + k0 + kk);
            a4[0] = fmaf(we, uu.x, a4[0]); a4[1] = fmaf(we, uu.y, a4[1]);
            a4[2] = fmaf(we, uu.z, a4[2]); a4[3] = fmaf(we, uu.w, a4[3]);
          }
          float inv = 1.f / L;
#pragma unroll
          for (int q = 0; q < 4; ++q){
            float c = a4[q]*inv;
            xll[(kk + q)*32 + bb] = c;
            if ((bid & 7) == 0) ctxall[(size_t)(t-1)*32768 + (size_t)bb*1024 + k0 + kk + q] = c;
          }
        }
        float acc[2][4] = {{0.f,0.f,0.f,0.f},{0.f,0.f,0.f,0.f}};
        const int tj = tid & 31, tr = tid >> 5;
        for (int kc = 0; kc < 2; ++kc){
          __syncthreads();
          {
            int j = tid >> 2, q2 = tid & 3;
            const float* Mrow = D + (size_t)(j0 + j)*1024 + k0 + kc*32;
#pragma unroll
            for (int c2 = 0; c2 < 2; ++c2){
              int quad = q2*2 + c2;
              float4 v = *(const float4*)(Mrow + quad*4);
              int kk = quad*4;
              wtlh[(kk+0)*128 + j] = v.x;
              wtlh[(kk+1)*128 + j] = v.y;
              wtlh[(kk+2)*128 + j] = v.z;
              wtlh[(kk+3)*128 + j] = v.w;
            }
          }
          __syncthreads();
#pragma unroll 4
          for (int k = 0; k < 32; ++k){
            float4 w4 = *(const float4*)(wtlh + k*128 + tj*4);
            float x0 = xll[(kc*32 + k)*32 + tr*2];
            float x1 = xll[(kc*32 + k)*32 + tr*2 + 1];
            acc[0][0] = fmaf(x0, w4.x, acc[0][0]);
            acc[0][1] = fmaf(x0, w4.y, acc[0][1]);
            acc[0][2] = fmaf(x0, w4.z, acc[0][2]);
            acc[0][3] = fmaf(x0, w4.w, acc[0][3]);
            acc[1][0] = fmaf(x1, w4.x, acc[1][0]);
            acc[1][1] = fmaf(x1, w4.y, acc[1][1]);
            acc[1][2] = fmaf(x1, w4.z, acc[1][2]);
            acc[1][3] = fmaf(x1, w4.w, acc[1][3]);
          }
        }
        const size_t base = ((size_t)kb*32 + tr*2)*1024 + j0 + tj*4;
        *(float4*)(partX + base)        = make_float4(acc[0][0], acc[0][1], acc[0][2], acc[0][3]);
        *(float4*)(partX + base + 1024) = make_float4(acc[1][0], acc[1][1], acc[1][2], acc[1][3]);
      }
      __threadfence();
      grid.sync();
      __threadfence();
    } else {
      if (bid < 16){
        const int k0 = bid*64;
        int bb = tid >> 4, kk = (tid & 15)*4;
        float mx = -1e30f;
#pragma unroll
        for (int i = 0; i < 16; ++i) mx = fmaxf(mx, mlp[((size_t)bb*16 + i)*2]);
        float L = 0.f;
        float a4[4] = {0.f,0.f,0.f,0.f};
#pragma unroll 4
        for (int i = 0; i < 16; ++i){
          float m = mlp[((size_t)bb*16 + i)*2];
          float l = mlp[((size_t)bb*16 + i)*2 + 1];
          float we = __expf(m - mx);
          L = fmaf(l, we, L);
          float4 uu = *(const float4*)(ctxp + ((size_t)bb*16 + i)*1024 + k0 + kk);
          a4[0] = fmaf(we, uu.x, a4[0]); a4[1] = fmaf(we, uu.y, a4[1]);
          a4[2] = fmaf(we, uu.z, a4[2]); a4[3] = fmaf(we, uu.w, a4[3]);
        }
        float inv = 1.f / L;
#pragma unroll
        for (int q = 0; q < 4; ++q)
          ctxall[(size_t)(Tn-2)*32768 + (size_t)bb*1024 + k0 + kk + q] = a4[q]*inv;
      }
    }
  }
}

// ---------------- fallback gen-loop kernels (R13, proven) ----------------
template<int FIRST>
__global__ __launch_bounds__(512, 4) void attend10(
    const float* __restrict__ hidden, const float* __restrict__ partq,
    const float* __restrict__ dk,
    float* __restrict__ ctxp, float* __restrict__ mlp, float* __restrict__ uh)
{
  const int b = blockIdx.y, p = blockIdx.x;
  const int tid = threadIdx.x, lane = tid & 63, w = tid >> 6;
  __shared__ float xq[1024];
  __shared__ float sM[8], sL[8];
  __shared__ float sacc[8*1024];

  const int s0 = p*32 + w*4;
  size_t ro[4];
#pragma unroll
  for (int i = 0; i < 4; ++i) ro[i] = ((size_t)(s0+i)*Bn + b)*Hn;
  float4 u[4][4];
#pragma unroll
  for (int i = 0; i < 4; ++i){
    const float4* rp = (const float4*)(hidden + ro[i]) + lane;
    u[i][0]=rp[0]; u[i][1]=rp[64]; u[i][2]=rp[128]; u[i][3]=rp[192];
  }
#pragma unroll
  for (int h0 = 0; h0 < 1024; h0 += 512){
    int c = h0 + tid;
    float s = dk ? dk[c] : 0.f;
#pragma unroll
    for (int i = 0; i < 16; ++i) s += partq[((size_t)(i*Bn + b))*1024 + c];
    xq[c] = s;
  }
  if (FIRST){
#pragma unroll
    for (int i = 0; i < 4; ++i){
      float4* wp = (float4*)(uh + ro[i]) + lane;
      wp[0]=u[i][0]; wp[64]=u[i][1]; wp[128]=u[i][2]; wp[192]=u[i][3];
    }
  }
  __syncthreads();
  const float4* xp = (const float4*)xq + lane;
  float4 q0 = xp[0], q1 = xp[64], q2 = xp[128], q3 = xp[192];

  float d[4];
#pragma unroll
  for (int i = 0; i < 4; ++i) d[i] = dot16(q0,q1,q2,q3, u[i][0],u[i][1],u[i][2],u[i][3]);
#pragma unroll
  for (int off = 32; off; off >>= 1){
#pragma unroll
    for (int i = 0; i < 4; ++i) d[i] += __shfl_xor(d[i], off);
  }
  float mw = fmaxf(fmaxf(d[0], d[1]), fmaxf(d[2], d[3]));
  sM[w] = mw;
  __syncthreads();
  float M = sM[0];
#pragma unroll
  for (int i = 1; i < 8; ++i) M = fmaxf(M, sM[i]);
  float wi[4], lw = 0.f;
#pragma unroll
  for (int i = 0; i < 4; ++i){ wi[i] = __expf(d[i] - M); lw += wi[i]; }
  float4 a0, a1, a2, a3;
  a0 = make_float4(wi[0]*u[0][0].x, wi[0]*u[0][0].y, wi[0]*u[0][0].z, wi[0]*u[0][0].w);
  a1 = make_float4(wi[0]*u[0][1].x, wi[0]*u[0][1].y, wi[0]*u[0][1].z, wi[0]*u[0][1].w);
  a2 = make_float4(wi[0]*u[0][2].x, wi[0]*u[0][2].y, wi[0]*u[0][2].z, wi[0]*u[0][2].w);
  a3 = make_float4(wi[0]*u[0][3].x, wi[0]*u[0][3].y, wi[0]*u[0][3].z, wi[0]*u[0][3].w);
#pragma unroll
  for (int i = 1; i < 4; ++i){
    a0.x = fmaf(wi[i], u[i][0].x, a0.x); a0.y = fmaf(wi[i], u[i][0].y, a0.y);
    a0.z = fmaf(wi[i], u[i][0].z, a0.z); a0.w = fmaf(wi[i], u[i][0].w, a0.w);
    a1.x = fmaf(wi[i], u[i][1].x, a1.x); a1.y = fmaf(wi[i], u[i][1].y, a1.y);
    a1.z = fmaf(wi[i], u[i][1].z, a1.z); a1.w = fmaf(wi[i], u[i][1].w, a1.w);
    a2.x = fmaf(wi[i], u[i][2].x, a2.x); a2.y = fmaf(wi[i], u[i][2].y, a2.y);
    a2.z = fmaf(wi[i], u[i][2].z, a2.z); a2.w = fmaf(wi[i], u[i][2].w, a2.w);
    a3.x = fmaf(wi[i], u[i][3].x, a3.x); a3.y = fmaf(wi[i], u[i][3].y, a3.y);
    a3.z = fmaf(wi[i], u[i][3].z, a3.z); a3.w = fmaf(wi[i], u[i][3].w, a3.w);
  }
  {
    int sl0 = (lane*4 + 0) ^ (lane & 7);
    int sl1 = (lane*4 + 1) ^ (lane & 7);
    int sl2 = (lane*4 + 2) ^ (lane & 7);
    int sl3 = (lane*4 + 3) ^ (lane & 7);
    *(float4*)(sacc + w*1024 + sl0*4) = a0;
    *(float4*)(sacc + w*1024 + sl1*4) = a1;
    *(float4*)(sacc + w*1024 + sl2*4) = a2;
    *(float4*)(sacc + w*1024 + sl3*4) = a3;
  }
  if (lane == 0) sL[w] = lw;
  __syncthreads();
#pragma unroll
  for (int h0 = 0; h0 < 1024; h0 += 512){
    int c = h0 + tid;
    int k = c >> 8, l = (c >> 2) & 63, j = c & 3;
    int fo = ((((l << 2) + k) ^ (l & 7)) << 2) + j;
    float s = 0.f;
#pragma unroll
    for (int i = 0; i < 8; ++i) s += sacc[i*1024 + fo];
    ctxp[((size_t)b*16 + p)*1024 + c] = s;
  }
  if (tid == 0){
    float L = 0.f;
#pragma unroll
    for (int i = 0; i < 8; ++i) L += sL[i];
    mlp[((size_t)b*16 + p)*2]     = M;
    mlp[((size_t)b*16 + p)*2 + 1] = L;
  }
}

template<int FULL>
__global__ __launch_bounds__(256) void genw(
    const float* __restrict__ ctxp, const float* __restrict__ mlp,
    const float* __restrict__ D, float* __restrict__ part, float* __restrict__ ctxout)
{
  __shared__ float wt[64*128];
  __shared__ float xl[64*32];
  const int t  = threadIdx.x;
  const int j0 = blockIdx.x * 128;
  const int kb = blockIdx.y;
  const int k0 = kb*64;
  const int tj = t & 31, tr = t >> 5;

  if (FULL){
    int j = t >> 1;
    int kqb = (t & 1) * 8;
    const float* Mrow = D + (size_t)(j0 + j)*1024 + k0;
#pragma unroll
    for (int c = 0; c < 8; ++c){
      float4 v = *(const float4*)(Mrow + (kqb + c)*4);
      int kk = (kqb + c)*4;
      wt[(kk+0)*128 + j] = v.x;
      wt[(kk+1)*128 + j] = v.y;
      wt[(kk+2)*128 + j] = v.z;
      wt[(kk+3)*128 + j] = v.w;
    }
  }
  {
    int b = t >> 3, kk = (t & 7)*8;
    float mx = -1e30f;
#pragma unroll
    for (int i = 0; i < 16; ++i) mx = fmaxf(mx, mlp[((size_t)b*16 + i)*2]);
    float L = 0.f;
    float a8[8] = {0.f,0.f,0.f,0.f,0.f,0.f,0.f,0.f};
#pragma unroll 4
    for (int i = 0; i < 16; ++i){
      float m = mlp[((size_t)b*16 + i)*2];
      float l = mlp[((size_t)b*16 + i)*2 + 1];
      float we = __expf(m - mx);
      L = fmaf(l, we, L);
      const float* cp = ctxp + ((size_t)b*16 + i)*1024 + k0 + kk;
      float4 u0 = *(const float4*)cp;
      float4 u1 = *(const float4*)(cp + 4);
      a8[0] = fmaf(we, u0.x, a8[0]); a8[1] = fmaf(we, u0.y, a8[1]);
      a8[2] = fmaf(we, u0.z, a8[2]); a8[3] = fmaf(we, u0.w, a8[3]);
      a8[4] = fmaf(we, u1.x, a8[4]); a8[5] = fmaf(we, u1.y, a8[5]);
      a8[6] = fmaf(we, u1.z, a8[6]); a8[7] = fmaf(we, u1.w, a8[7]);
    }
    float inv = 1.f / L;
#pragma unroll
    for (int q = 0; q < 8; ++q){
      float c = a8[q]*inv;
      if (FULL) xl[(kk + q)*32 + b] = c;
      if (!FULL || blockIdx.x == 0) ctxout[(size_t)b*1024 + k0 + kk + q] = c;
    }
  }
  if (!FULL) return;
  __syncthreads();
  float acc[4][4] = {{0.f,0.f,0.f,0.f},{0.f,0.f,0.f,0.f},{0.f,0.f,0.f,0.f},{0.f,0.f,0.f,0.f}};
#pragma unroll 4
  for (int k = 0; k < 64; ++k){
    float4 w4 = *(const float4*)(wt + k*128 + tj*4);
    float4 x4 = *(const float4*)(xl + k*32  + tr*4);
    acc[0][0] = fmaf(x4.x, w4.x, acc[0][0]);
    acc[0][1] = fmaf(x4.x, w4.y, acc[0][1]);
    acc[0][2] = fmaf(x4.x, w4.z, acc[0][2]);
    acc[0][3] = fmaf(x4.x, w4.w, acc[0][3]);
    acc[1][0] = fmaf(x4.y, w4.x, acc[1][0]);
    acc[1][1] = fmaf(x4.y, w4.y, acc[1][1]);
    acc[1][2] = fmaf(x4.y, w4.z, acc[1][2]);
    acc[1][3] = fmaf(x4.y, w4.w, acc[1][3]);
    acc[2][0] = fmaf(x4.z, w4.x, acc[2][0]);
    acc[2][1] = fmaf(x4.z, w4.y, acc[2][1]);
    acc[2][2] = fmaf(x4.z, w4.z, acc[2][2]);
    acc[2][3] = fmaf(x4.z, w4.w, acc[2][3]);
    acc[3][0] = fmaf(x4.w, w4.x, acc[3][0]);
    acc[3][1] = fmaf(x4.w, w4.y, acc[3][1]);
    acc[3][2] = fmaf(x4.w, w4.z, acc[3][2]);
    acc[3][3] = fmaf(x4.w, w4.w, acc[3][3]);
  }
  const size_t base = ((size_t)kb*32 + tr*4)*1024 + j0 + tj*4;
#pragma unroll
  for (int i = 0; i < 4; ++i)
    *(float4*)(part + base + (size_t)i*1024) = make_float4(acc[i][0], acc[i][1], acc[i][2], acc[i][3]);
}

// ---------------- split-K register-tiled matvec ----------------
__global__ __launch_bounds__(256) void mv1(
    const float* __restrict__ X, int xstride,
    const float* __restrict__ M, float* __restrict__ part,
    int nj, int ktiles)
{
  __shared__ float wt[64*128];
  __shared__ float xl[64*32];
  const int t  = threadIdx.x;
  const int j0 = blockIdx.x * 128;
  const int kb = blockIdx.y;
  const int r0 = blockIdx.z * 32;
  const int R  = gridDim.z * 32;
  const int tj = t & 31, tr = t >> 5;
  float acc[4][4] = {{0.f,0.f,0.f,0.f},{0.f,0.f,0.f,0.f},{0.f,0.f,0.f,0.f},{0.f,0.f,0.f,0.f}};

  for (int kt = 0; kt < ktiles; ++kt){
    const int k0 = (kb*ktiles + kt)*64;
    __syncthreads();
    {
      int j = t >> 1;
      int kqb = (t & 1) * 8;
      const float* Mrow = M + (size_t)(j0 + j)*1024 + k0;
#pragma unroll
      for (int c = 0; c < 8; ++c){
        float4 v = *(const float4*)(Mrow + (kqb + c)*4);
        int kk = (kqb + c)*4;
        wt[(kk+0)*128 + j] = v.x;
        wt[(kk+1)*128 + j] = v.y;
        wt[(kk+2)*128 + j] = v.z;
        wt[(kk+3)*128 + j] = v.w;
      }
      int r = t >> 3;
      int kq0 = t & 7;
#pragma unroll
      for (int c = 0; c < 2; ++c){
        int kk = (kq0 + c*8)*4;
        float4 v = *(const float4*)(X + (size_t)(r0 + r)*xstride + k0 + kk);
        xl[(kk+0)*32 + r] = v.x;
        xl[(kk+1)*32 + r] = v.y;
        xl[(kk+2)*32 + r] = v.z;
        xl[(kk+3)*32 + r] = v.w;
      }
    }
    __syncthreads();
#pragma unroll 4
    for (int k = 0; k < 64; ++k){
      float4 w4 = *(const float4*)(wt + k*128 + tj*4);
      float4 x4 = *(const float4*)(xl + k*32  + tr*4);
      acc[0][0] = fmaf(x4.x, w4.x, acc[0][0]);
      acc[0][1] = fmaf(x4.x, w4.y, acc[0][1]);
      acc[0][2] = fmaf(x4.x, w4.z, acc[0][2]);
      acc[0][3] = fmaf(x4.x, w4.w, acc[0][3]);
      acc[1][0] = fmaf(x4.y, w4.x, acc[1][0]);
      acc[1][1] = fmaf(x4.y, w4.y, acc[1][1]);
      acc[1][2] = fmaf(x4.y, w4.z, acc[1][2]);
      acc[1][3] = fmaf(x4.y, w4.w, acc[1][3]);
      acc[2][0] = fmaf(x4.z, w4.x, acc[2][0]);
      acc[2][1] = fmaf(x4.z, w4.y, acc[2][1]);
      acc[2][2] = fmaf(x4.z, w4.z, acc[2][2]);
      acc[2][3] = fmaf(x4.z, w4.w, acc[2][3]);
      acc[3][0] = fmaf(x4.w, w4.x, acc[3][0]);
      acc[3][1] = fmaf(x4.w, w4.y, acc[3][1]);
      acc[3][2] = fmaf(x4.w, w4.z, acc[3][2]);
      acc[3][3] = fmaf(x4.w, w4.w, acc[3][3]);
    }
  }
  const size_t base = ((size_t)kb*R + r0 + tr*4)*nj + j0 + tj*4;
#pragma unroll
  for (int i = 0; i < 4; ++i)
    *(float4*)(part + base + (size_t)i*nj) = make_float4(acc[i][0], acc[i][1], acc[i][2], acc[i][3]);
}

__global__ __launch_bounds__(256) void mv2(
    const float* __restrict__ part, int R, int njshift, int KB,
    const float* __restrict__ b1, const float* __restrict__ b2,
    float* __restrict__ out, int rpgshift, int opg)
{
  int idx = blockIdx.x*256 + threadIdx.x;
  int nj = 1 << njshift;
  int r = idx >> njshift, j = idx & (nj - 1);
  float s = 0.f;
  if (b1) s += b1[j];
  if (b2) s += b2[j];
  size_t stride = (size_t)R << njshift;
  for (int kb = 0; kb < KB; ++kb) s += part[(size_t)kb*stride + idx];
  int orow = ((r >> rpgshift) * opg) + (r & ((1 << rpgshift) - 1));
  out[((size_t)orow << njshift) + j] = s;
}

// reduce batched Wv partials -> xs[b][t+1] (+bv). KB=16, R=224. grid 896.
__global__ __launch_bounds__(256) void mv2xs(
    const float* __restrict__ part, const float* __restrict__ bv, float* __restrict__ xs)
{
  int idx = blockIdx.x*256 + threadIdx.x;
  int r = idx >> 10, j = idx & 1023;
  int t = r >> 5, b = r & 31;
  const size_t stride = (size_t)224*1024;
  float s = bv[j];
#pragma unroll
  for (int kb = 0; kb < 16; ++kb) s += part[(size_t)kb*stride + idx];
  xs[(((size_t)b*Tn) + t + 1)*1024 + j] = s;
}

// ---------------- stage-2 kernels (R13 variants) ----------------

__global__ __launch_bounds__(512) void scores2_kernel(
    const float* __restrict__ hidden, const float* __restrict__ xk2, float* __restrict__ sc)
{
  int b = blockIdx.y, p = blockIdx.x;
  int lane = threadIdx.x & 63, w = threadIdx.x >> 6;
  int t0 = (w & 3) * 2, rh = w >> 2;
  const float4* qa = (const float4*)(xk2 + ((size_t)b*Tn + t0  )*Hn) + lane;
  const float4* qb = (const float4*)(xk2 + ((size_t)b*Tn + t0+1)*Hn) + lane;
  float4 a0=qa[0], a1=qa[64], a2=qa[128], a3=qa[192];
  float4 c0=qb[0], c1=qb[64], c2=qb[128], c3=qb[192];
#pragma unroll 2
  for (int r = 0; r < 8; ++r){
    int s = p*16 + rh*8 + r;
    const float4* row = (const float4*)(hidden + ((size_t)s*Bn + b)*Hn) + lane;
    float4 v0=row[0], v1=row[64], v2=row[128], v3=row[192];
    float d0 = wsum(dot16(a0,a1,a2,a3, v0,v1,v2,v3));
    float d1 = wsum(dot16(c0,c1,c2,c3, v0,v1,v2,v3));
    if (lane == 0){
      sc[((size_t)b*Tn + t0  )*Sn + s] = d0;
      sc[((size_t)b*Tn + t0+1)*Sn + s] = d1;
    }
  }
}

__global__ __launch_bounds__(512) void softmax512(float* __restrict__ sc){
  int row = blockIdx.x, tid = threadIdx.x, lane = tid & 63, w = tid >> 6;
  float v = sc[(size_t)row*Sn + tid];
  float mx = v;
#pragma unroll
  for (int off = 32; off; off >>= 1) mx = fmaxf(mx, __shfl_xor(mx, off));
  __shared__ float sm[8], ss[8];
  if (lane == 0) sm[w] = mx;
  __syncthreads();
  mx = sm[0];
#pragma unroll
  for (int i = 1; i < 8; ++i) mx = fmaxf(mx, sm[i]);
  float e = __expf(v - mx);
  float s = e;
#pragma unroll
  for (int off = 32; off; off >>= 1) s += __shfl_xor(s, off);
  if (lane == 0) ss[w] = s;
  __syncthreads();
  float tot = 0.f;
#pragma unroll
  for (int i = 0; i < 8; ++i) tot += ss[i];
  sc[(size_t)row*Sn + tid] = e / tot;
}

__global__ __launch_bounds__(512) void ctx2p(
    const float* __restrict__ hidden, const float* __restrict__ attn, float* __restrict__ part)
{
  int hc = blockIdx.x, sc = blockIdx.y, b = blockIdx.z;
  int tid = threadIdx.x, hloc = tid & 127, tg = tid >> 7;
  __shared__ float al[Tn*128];
  for (int idx = tid; idx < Tn*128; idx += 512){
    int t = idx >> 7, si = idx & 127;
    al[idx] = attn[((size_t)b*Tn + t)*Sn + sc*128 + si];
  }
  __syncthreads();
  int h = hc*128 + hloc, t0 = tg*2;
  float acc0 = 0.f, acc1 = 0.f;
#pragma unroll 4
  for (int si = 0; si < 128; ++si){
    int s = sc*128 + si;
    float v = hidden[((size_t)s*Bn + b)*Hn + h];
    acc0 = fmaf(al[t0*128 + si],     v, acc0);
    acc1 = fmaf(al[(t0+1)*128 + si], v, acc1);
  }
  part[(((size_t)sc*Bn + b)*Tn + t0  )*Hn + h] = acc0;
  part[(((size_t)sc*Bn + b)*Tn + t0+1)*Hn + h] = acc1;
}

__global__ __launch_bounds__(256) void ctx2r(const float* __restrict__ part, float* __restrict__ out){
  int idx = blockIdx.x*256 + threadIdx.x;
  out[idx] = part[idx] + part[262144 + idx] + part[524288 + idx] + part[786432 + idx];
}

// ---------------- LSTM: fused partial-reduce + pointwise ----------------
__global__ __launch_bounds__(256) void lstm_fused(
    const float* __restrict__ part, const float* __restrict__ b_ih,
    const float* __restrict__ b_hh, float* __restrict__ fq)
{
  int idx = blockIdx.x*256 + threadIdx.x;
  int b = idx >> 10, h = idx & 1023;
  const size_t stride = (size_t)32*Gn;
  float gi = b_ih[h] + b_hh[h];
  float gg = b_ih[2048+h] + b_hh[2048+h];
  float go = b_ih[3072+h] + b_hh[3072+h];
  for (int kb = 0; kb < 16; ++kb){
    const float* pp = part + (size_t)kb*stride + (size_t)b*Gn;
    gi += pp[h]; gg += pp[2048+h]; go += pp[3072+h];
  }
  float si = 1.f/(1.f + __expf(-gi));
  float so = 1.f/(1.f + __expf(-go));
  float c  = si * tanhf(gg);
  fq[((size_t)b*(Tn+1) + Tn)*Hn + h] = so * tanhf(c);
}

// ---------------- host ----------------

extern "C" void kernel_launch(void* const* d_in, const int* in_sizes, int n_in,
                              void* d_out, int out_size, void* d_ws, size_t ws_size,
                              hipStream_t stream) {
  const float* hidden = (const float*)d_in[0];
  const float* nums   = (const float*)d_in[1];
  const float* pq     = (const float*)d_in[2];
  const float* Wk     = (const float*)d_in[3];
  const float* Wv     = (const float*)d_in[5];
  const float* bv     = (const float*)d_in[6];
  const float* Wk2    = (const float*)d_in[7];
  const float* Wv2    = (const float*)d_in[9];
  const float* bv2    = (const float*)d_in[10];
  const float* W_ih   = (const float*)d_in[11];
  const float* b_ih   = (const float*)d_in[13];
  const float* b_hh   = (const float*)d_in[14];

  float* out = (float*)d_out;
  float* fq  = out;                                   // (B, T+1, H)
  float* uh  = out + (size_t)Bn*(Tn+1)*Hn;            // (S+T, B, H)
  float* un  = uh + (size_t)(Sn+Tn)*Bn*Hn;            // (B, N+T, H)

  // ws layout (floats); high-water 11,668,480 floats = 46.7 MB (proven >= 56 MB available)
  float* ws    = (float*)d_ws;
  float* xs    = ws;                 // 262144
  float* ctxp  = ws + 262144;        // 524288 (B*16*H)
  float* mlp   = ws + 1310720;       // 1024
  float* xk2   = ws + 1345536;       // 262144
  float* sc2   = ws + 1607680;       // 131072
  float* ctx2v = ws + 1738752;       // 262144
  float* partX = ws + 2000896;       // 524288 (16*32*1024)
  float* partK = ws + 2525184;       // 524288
  float* WkT   = ws + 3049472;       // 1048576
  float* Wk2T  = ws + 4098048;       // 1048576
  float* WvT   = ws + 5146624;       // 1048576
  float* Dcomb = ws + 6195200;       // 1048576
  float* ctxall= ws + 7243776;       // 229376 (7*32*1024)
  float* dk    = ws + 7473152;       // 1024
  float* Dparts= ws + 7474176;       // 4194304 (split-K partials)
  float* c2part= partX;              // ctx2 partials (spans partX+partK, disjoint lifetime)
  float* partL = WkT;                // LSTM partials (WkT/Wk2T dead by then; rewritten each call)

  transprep<<<dim3(32,32,4), 256, 0, stream>>>(Wk, Wk2, Wv, WkT, Wk2T, WvT,
      (const float4*)nums, (const float4*)pq, (float4*)un, (float4*)xs);
  mv1<<<dim3(8,4,32), 256, 0, stream>>>(WkT, Hn, WvT, Dparts, Hn, 4);
  dred<<<4352, 256, 0, stream>>>(Dparts, Dcomb, bv, WkT, dk);
  mv1<<<dim3(8,16,1), 256, 0, stream>>>(pq, Hn, WkT, partK, Hn, 1);

  // persistent cooperative gen loop; fall back to the proven R13 sequence if
  // the cooperative launch is rejected (capacity/capture) -- identical math.
  bool coop_ok = false;
  {
    void* args[] = {(void*)&hidden, (void*)&partK, (void*)&dk, (void*)&Dcomb,
                    (void*)&partX, (void*)&ctxp, (void*)&mlp, (void*)&ctxall, (void*)&uh};
    hipError_t ce = hipLaunchCooperativeKernel((const void*)coop_gen, dim3(512), dim3(512),
                                               args, 0, stream);
    coop_ok = (ce == hipSuccess);
  }
  if (!coop_ok){
    for (int t = 1; t < Tn; ++t){
      if (t == 1) attend10<1><<<dim3(16,Bn), 512, 0, stream>>>(hidden, partK, nullptr, ctxp, mlp, uh);
      else        attend10<0><<<dim3(16,Bn), 512, 0, stream>>>(hidden, partX, dk, ctxp, mlp, uh);
      float* ctxt = ctxall + (size_t)(t-1)*Bn*Hn;
      if (t < Tn-1) genw<1><<<dim3(8,16), 256, 0, stream>>>(ctxp, mlp, Dcomb, partX, ctxt);
      else          genw<0><<<dim3(1,16), 256, 0, stream>>>(ctxp, mlp, Dcomb, partX, ctxt);
    }
  }

  // xs[:,1..7,:] = ctxall @ Wv^T + bv  (batched; KB=16)
  mv1<<<dim3(8,16,7), 256, 0, stream>>>(ctxall, Hn, Wv, Dparts, Hn, 1);
  mv2xs<<<896, 256, 0, stream>>>(Dparts, bv, xs);

  // stage 2
  mv1<<<dim3(8,16,8), 256, 0, stream>>>(xs, Hn, Wk2T, Dparts, Hn, 1);
  mv2<<<1024, 256, 0, stream>>>(Dparts, 256, 10, 16, nullptr, nullptr, xk2, 0, 1);
  scores2_kernel<<<dim3(32, Bn), 512, 0, stream>>>(hidden, xk2, sc2);
  softmax512<<<Bn*Tn, 512, 0, stream>>>(sc2);
  ctx2p<<<dim3(8, 4, Bn), 512, 0, stream>>>(hidden, sc2, c2part);
  ctx2r<<<1024, 256, 0, stream>>>(c2part, ctx2v);
  mv1<<<dim3(8,16,8), 256, 0, stream>>>(ctx2v, Hn, Wv2, Dparts, Hn, 1);
  mv2<<<1024, 256, 0, stream>>>(Dparts, 256, 10, 16, bv2, nullptr, fq, 3, Tn+1);

  // LSTM step 1 (partials overlay WkT/Wk2T -- dead by now)
  mv1<<<dim3(32,16,1), 256, 0, stream>>>(fq, (Tn+1)*Hn, W_ih, partL, Gn, 1);
  lstm_fused<<<128, 256, 0, stream>>>(partL, b_ih, b_hh, fq);

  finalize_xs<<<dim3(Tn, Bn), 256, 0, stream>>>((const float4*)xs, (float4*)uh, (float4*)un);
}

// Round 17
// 438.484 us; speedup vs baseline: 6.3735x; 6.3735x over previous
//
#include <hip/hip_runtime.h>
#include <math.h>

#define Bn 32
#define Sn 512
#define Hn 1024
#define Tn 8
#define Nn 16
#define Gn 4096

__device__ __forceinline__ float wsum(float v){
#pragma unroll
  for (int off = 32; off; off >>= 1) v += __shfl_xor(v, off);
  return v;
}

__device__ __forceinline__ float dot16(float4 a0, float4 a1, float4 a2, float4 a3,
                                       float4 v0, float4 v1, float4 v2, float4 v3){
  float d = a0.x*v0.x + a0.y*v0.y + a0.z*v0.z + a0.w*v0.w;
  d += a1.x*v1.x + a1.y*v1.y + a1.z*v1.z + a1.w*v1.w;
  d += a2.x*v2.x + a2.y*v2.y + a2.z*v2.z + a2.w*v2.w;
  d += a3.x*v3.x + a3.y*v3.y + a3.z*v3.z + a3.w*v3.w;
  return d;
}

// ---------------- prep: 3 transposes + nums/pq copies in ONE launch ----------
__global__ __launch_bounds__(256) void transprep(
    const float* __restrict__ Wk, const float* __restrict__ Wk2, const float* __restrict__ Wv,
    float* __restrict__ WkT, float* __restrict__ Wk2T, float* __restrict__ WvT,
    const float4* __restrict__ nums, const float4* __restrict__ pq,
    float4* __restrict__ un, float4* __restrict__ xs){
  if (blockIdx.z == 3){
    int n = blockIdx.x, b = blockIdx.y;
    if (n < Nn) un[((size_t)b*(Nn+Tn) + n)*256 + threadIdx.x] = nums[((size_t)b*Nn + n)*256 + threadIdx.x];
    else if (n == Nn) xs[((size_t)b*Tn)*256 + threadIdx.x] = pq[(size_t)b*256 + threadIdx.x];
    return;
  }
  __shared__ float tile[32][33];
  const float* in  = (blockIdx.z == 0) ? Wk  : (blockIdx.z == 1) ? Wk2  : Wv;
  float*       outp= (blockIdx.z == 0) ? WkT : (blockIdx.z == 1) ? Wk2T : WvT;
  int tx = threadIdx.x & 31, ty = threadIdx.x >> 5;
  int c0 = blockIdx.x * 32, r0 = blockIdx.y * 32;
#pragma unroll
  for (int k = 0; k < 4; ++k)
    tile[ty + 8*k][tx] = in[(size_t)(r0 + ty + 8*k) * Hn + c0 + tx];
  __syncthreads();
#pragma unroll
  for (int k = 0; k < 4; ++k)
    outp[(size_t)(c0 + ty + 8*k) * Hn + r0 + tx] = tile[tx][ty + 8*k];
}

__global__ __launch_bounds__(256) void finalize_xs(const float4* __restrict__ xs, float4* __restrict__ uh, float4* __restrict__ un){
  int t = blockIdx.x, b = blockIdx.y;
  float4 v = xs[((size_t)b*Tn + t)*256 + threadIdx.x];
  uh[(((size_t)(Sn + t))*Bn + b)*256 + threadIdx.x] = v;
  un[((size_t)b*(Nn+Tn) + Nn + t)*256 + threadIdx.x] = v;
}

// ---------------- dred: Dcomb split-K reduce + dkv fused. grid 4352 ----------
__global__ __launch_bounds__(256) void dred(
    const float* __restrict__ Dparts, float* __restrict__ Dcomb,
    const float* __restrict__ bv, const float* __restrict__ WkT, float* __restrict__ dk)
{
  if (blockIdx.x < 4096){
    int idx = blockIdx.x*256 + threadIdx.x;
    const size_t stride = (size_t)1024*1024;
    float s = Dparts[idx] + Dparts[stride + idx] + Dparts[2*stride + idx] + Dparts[3*stride + idx];
    Dcomb[idx] = s;
  } else {
    int lane = threadIdx.x & 63, w = threadIdx.x >> 6;
    int j = (blockIdx.x - 4096)*4 + w;
    const float4* rp = (const float4*)(WkT + (size_t)j*Hn) + lane;
    const float4* bp = (const float4*)bv + lane;
    float4 v0=rp[0], v1=rp[64], v2=rp[128], v3=rp[192];
    float4 b0=bp[0], b1=bp[64], b2=bp[128], b3=bp[192];
    float d = wsum(dot16(b0,b1,b2,b3, v0,v1,v2,v3));
    if (lane == 0) dk[j] = d;
  }
}

// zero the per-(step,b) barrier counters (224 counters, stride 16 uints)
__global__ void zcnt(unsigned* __restrict__ cnt){
  cnt[(size_t)threadIdx.x * 16] = 0u;
}

// ---------------- attend11: attend + per-b barrier + fused combine/q-slice --
// grid 512 (p = bid&15, b = bid>>4), block 512 = 8 waves x 4 rows.
// Phase A: q read direct (4KB), 32-row weighted accumulate -> ctxp[b][p], mlp.
// Barrier: syncthreads (stores->L2), tid0: threadfence (wbl2) + atomicAdd;
// spin until all 16 blocks of b signal (bounded -> never hangs).
// Phase B: every block combines full ctx into LDS; writes its 64-slice of
// ctxall; if !LAST computes q_next[j] = dk[j] + sum_k D[j][k] ctx[k] for its
// 64-j slice -> xkq (single buffer: only b's own slice, all b-readers done).
template<int FIRST, int LAST>
__global__ __launch_bounds__(512, 4) void attend11(
    const float* __restrict__ hidden, const float* __restrict__ xkq_in,
    const float* __restrict__ dk, const float* __restrict__ D,
    float* __restrict__ ctxp, float* __restrict__ mlp,
    float* __restrict__ xkq_out, float* __restrict__ ctxout,
    unsigned* __restrict__ cnt, float* __restrict__ uh)
{
  const int bid = blockIdx.x;
  const int p = bid & 15, b = bid >> 4;
  const int tid = threadIdx.x, lane = tid & 63, w = tid >> 6;
  __shared__ float sacc[8*1024];
  __shared__ float ctxs[1024];
  __shared__ float sM[8], sL[8];

  // ---- phase A: attend ----
  const float4* xp = (const float4*)(xkq_in + (size_t)b*Hn) + lane;
  float4 q0 = xp[0], q1 = xp[64], q2 = xp[128], q3 = xp[192];

  const int s0 = p*32 + w*4;
  size_t ro[4];
#pragma unroll
  for (int i = 0; i < 4; ++i) ro[i] = ((size_t)(s0+i)*Bn + b)*Hn;
  float4 u[4][4];
#pragma unroll
  for (int i = 0; i < 4; ++i){
    const float4* rp = (const float4*)(hidden + ro[i]) + lane;
    u[i][0]=rp[0]; u[i][1]=rp[64]; u[i][2]=rp[128]; u[i][3]=rp[192];
  }
  if (FIRST){
#pragma unroll
    for (int i = 0; i < 4; ++i){
      float4* wp = (float4*)(uh + ro[i]) + lane;
      wp[0]=u[i][0]; wp[64]=u[i][1]; wp[128]=u[i][2]; wp[192]=u[i][3];
    }
  }
  float d[4];
#pragma unroll
  for (int i = 0; i < 4; ++i) d[i] = dot16(q0,q1,q2,q3, u[i][0],u[i][1],u[i][2],u[i][3]);
#pragma unroll
  for (int off = 32; off; off >>= 1){
#pragma unroll
    for (int i = 0; i < 4; ++i) d[i] += __shfl_xor(d[i], off);
  }
  float mw = fmaxf(fmaxf(d[0], d[1]), fmaxf(d[2], d[3]));
  sM[w] = mw;
  __syncthreads();
  float M = sM[0];
#pragma unroll
  for (int i = 1; i < 8; ++i) M = fmaxf(M, sM[i]);
  float wi[4], lw = 0.f;
#pragma unroll
  for (int i = 0; i < 4; ++i){ wi[i] = __expf(d[i] - M); lw += wi[i]; }
  float4 a0, a1, a2, a3;
  a0 = make_float4(wi[0]*u[0][0].x, wi[0]*u[0][0].y, wi[0]*u[0][0].z, wi[0]*u[0][0].w);
  a1 = make_float4(wi[0]*u[0][1].x, wi[0]*u[0][1].y, wi[0]*u[0][1].z, wi[0]*u[0][1].w);
  a2 = make_float4(wi[0]*u[0][2].x, wi[0]*u[0][2].y, wi[0]*u[0][2].z, wi[0]*u[0][2].w);
  a3 = make_float4(wi[0]*u[0][3].x, wi[0]*u[0][3].y, wi[0]*u[0][3].z, wi[0]*u[0][3].w);
#pragma unroll
  for (int i = 1; i < 4; ++i){
    a0.x = fmaf(wi[i], u[i][0].x, a0.x); a0.y = fmaf(wi[i], u[i][0].y, a0.y);
    a0.z = fmaf(wi[i], u[i][0].z, a0.z); a0.w = fmaf(wi[i], u[i][0].w, a0.w);
    a1.x = fmaf(wi[i], u[i][1].x, a1.x); a1.y = fmaf(wi[i], u[i][1].y, a1.y);
    a1.z = fmaf(wi[i], u[i][1].z, a1.z); a1.w = fmaf(wi[i], u[i][1].w, a1.w);
    a2.x = fmaf(wi[i], u[i][2].x, a2.x); a2.y = fmaf(wi[i], u[i][2].y, a2.y);
    a2.z = fmaf(wi[i], u[i][2].z, a2.z); a2.w = fmaf(wi[i], u[i][2].w, a2.w);
    a3.x = fmaf(wi[i], u[i][3].x, a3.x); a3.y = fmaf(wi[i], u[i][3].y, a3.y);
    a3.z = fmaf(wi[i], u[i][3].z, a3.z); a3.w = fmaf(wi[i], u[i][3].w, a3.w);
  }
  {
    int sl0 = (lane*4 + 0) ^ (lane & 7);
    int sl1 = (lane*4 + 1) ^ (lane & 7);
    int sl2 = (lane*4 + 2) ^ (lane & 7);
    int sl3 = (lane*4 + 3) ^ (lane & 7);
    *(float4*)(sacc + w*1024 + sl0*4) = a0;
    *(float4*)(sacc + w*1024 + sl1*4) = a1;
    *(float4*)(sacc + w*1024 + sl2*4) = a2;
    *(float4*)(sacc + w*1024 + sl3*4) = a3;
  }
  if (lane == 0) sL[w] = lw;
  __syncthreads();
#pragma unroll
  for (int h0 = 0; h0 < 1024; h0 += 512){
    int c = h0 + tid;
    int k = c >> 8, l = (c >> 2) & 63, j = c & 3;
    int fo = ((((l << 2) + k) ^ (l & 7)) << 2) + j;
    float s = 0.f;
#pragma unroll
    for (int i = 0; i < 8; ++i) s += sacc[i*1024 + fo];
    ctxp[((size_t)b*16 + p)*1024 + c] = s;
  }
  if (tid == 0){
    float L = 0.f;
#pragma unroll
    for (int i = 0; i < 8; ++i) L += sL[i];
    mlp[((size_t)b*16 + p)*2]     = M;
    mlp[((size_t)b*16 + p)*2 + 1] = lw*0.f + L;
  }

  // ---- per-b barrier (16 blocks) ----
  __syncthreads();                       // all ctxp/mlp stores drained to L2
  if (tid == 0){
    __threadfence();                     // L2 writeback -> coherent point
    atomicAdd(cnt + (size_t)b*16, 1u);   // signal (device-scope RMW)
    unsigned it = 0;
    while (atomicAdd(cnt + (size_t)b*16, 0u) < 16u && it < (1u<<20)){
      ++it;
      __builtin_amdgcn_s_sleep(2);
    }
  }
  __syncthreads();

  // ---- phase B: combine full ctx + slice outputs ----
  float wex[16];
  float M2 = -1e30f, Lc = 0.f;
#pragma unroll
  for (int i = 0; i < 16; ++i) M2 = fmaxf(M2, mlp[((size_t)b*16 + i)*2]);
#pragma unroll
  for (int i = 0; i < 16; ++i){
    float e = __expf(mlp[((size_t)b*16 + i)*2] - M2);
    wex[i] = e;
    Lc = fmaf(mlp[((size_t)b*16 + i)*2 + 1], e, Lc);
  }
  float inv = 1.f / Lc;
#pragma unroll
  for (int h0 = 0; h0 < 1024; h0 += 512){
    int c = h0 + tid;
    float s = 0.f;
#pragma unroll
    for (int i = 0; i < 16; ++i) s = fmaf(wex[i], ctxp[((size_t)b*16 + i)*1024 + c], s);
    ctxs[c] = s * inv;
  }
  __syncthreads();
  if (tid < 64) ctxout[(size_t)b*Hn + p*64 + tid] = ctxs[p*64 + tid];
  if (!LAST){
    const float4* cx = (const float4*)ctxs + lane;
    float4 c0 = cx[0], c1 = cx[64], c2 = cx[128], c3 = cx[192];
#pragma unroll
    for (int jj = 0; jj < 8; ++jj){
      int j = p*64 + w*8 + jj;
      const float4* Dr = (const float4*)(D + (size_t)j*Hn) + lane;
      float4 e0 = Dr[0], e1 = Dr[64], e2 = Dr[128], e3 = Dr[192];
      float s = wsum(dot16(c0,c1,c2,c3, e0,e1,e2,e3));
      if (lane == 0) xkq_out[(size_t)b*Hn + j] = s + dk[j];
    }
  }
}

// ---------------- split-K register-tiled matvec ----------------
__global__ __launch_bounds__(256) void mv1(
    const float* __restrict__ X, int xstride,
    const float* __restrict__ M, float* __restrict__ part,
    int nj, int ktiles)
{
  __shared__ float wt[64*128];
  __shared__ float xl[64*32];
  const int t  = threadIdx.x;
  const int j0 = blockIdx.x * 128;
  const int kb = blockIdx.y;
  const int r0 = blockIdx.z * 32;
  const int R  = gridDim.z * 32;
  const int tj = t & 31, tr = t >> 5;
  float acc[4][4] = {{0.f,0.f,0.f,0.f},{0.f,0.f,0.f,0.f},{0.f,0.f,0.f,0.f},{0.f,0.f,0.f,0.f}};

  for (int kt = 0; kt < ktiles; ++kt){
    const int k0 = (kb*ktiles + kt)*64;
    __syncthreads();
    {
      int j = t >> 1;
      int kqb = (t & 1) * 8;
      const float* Mrow = M + (size_t)(j0 + j)*1024 + k0;
#pragma unroll
      for (int c = 0; c < 8; ++c){
        float4 v = *(const float4*)(Mrow + (kqb + c)*4);
        int kk = (kqb + c)*4;
        wt[(kk+0)*128 + j] = v.x;
        wt[(kk+1)*128 + j] = v.y;
        wt[(kk+2)*128 + j] = v.z;
        wt[(kk+3)*128 + j] = v.w;
      }
      int r = t >> 3;
      int kq0 = t & 7;
#pragma unroll
      for (int c = 0; c < 2; ++c){
        int kk = (kq0 + c*8)*4;
        float4 v = *(const float4*)(X + (size_t)(r0 + r)*xstride + k0 + kk);
        xl[(kk+0)*32 + r] = v.x;
        xl[(kk+1)*32 + r] = v.y;
        xl[(kk+2)*32 + r] = v.z;
        xl[(kk+3)*32 + r] = v.w;
      }
    }
    __syncthreads();
#pragma unroll 4
    for (int k = 0; k < 64; ++k){
      float4 w4 = *(const float4*)(wt + k*128 + tj*4);
      float4 x4 = *(const float4*)(xl + k*32  + tr*4);
      acc[0][0] = fmaf(x4.x, w4.x, acc[0][0]);
      acc[0][1] = fmaf(x4.x, w4.y, acc[0][1]);
      acc[0][2] = fmaf(x4.x, w4.z, acc[0][2]);
      acc[0][3] = fmaf(x4.x, w4.w, acc[0][3]);
      acc[1][0] = fmaf(x4.y, w4.x, acc[1][0]);
      acc[1][1] = fmaf(x4.y, w4.y, acc[1][1]);
      acc[1][2] = fmaf(x4.y, w4.z, acc[1][2]);
      acc[1][3] = fmaf(x4.y, w4.w, acc[1][3]);
      acc[2][0] = fmaf(x4.z, w4.x, acc[2][0]);
      acc[2][1] = fmaf(x4.z, w4.y, acc[2][1]);
      acc[2][2] = fmaf(x4.z, w4.z, acc[2][2]);
      acc[2][3] = fmaf(x4.z, w4.w, acc[2][3]);
      acc[3][0] = fmaf(x4.w, w4.x, acc[3][0]);
      acc[3][1] = fmaf(x4.w, w4.y, acc[3][1]);
      acc[3][2] = fmaf(x4.w, w4.z, acc[3][2]);
      acc[3][3] = fmaf(x4.w, w4.w, acc[3][3]);
    }
  }
  const size_t base = ((size_t)kb*R + r0 + tr*4)*nj + j0 + tj*4;
#pragma unroll
  for (int i = 0; i < 4; ++i)
    *(float4*)(part + base + (size_t)i*nj) = make_float4(acc[i][0], acc[i][1], acc[i][2], acc[i][3]);
}

__global__ __launch_bounds__(256) void mv2(
    const float* __restrict__ part, int R, int njshift, int KB,
    const float* __restrict__ b1, const float* __restrict__ b2,
    float* __restrict__ out, int rpgshift, int opg)
{
  int idx = blockIdx.x*256 + threadIdx.x;
  int nj = 1 << njshift;
  int r = idx >> njshift, j = idx & (nj - 1);
  float s = 0.f;
  if (b1) s += b1[j];
  if (b2) s += b2[j];
  size_t stride = (size_t)R << njshift;
  for (int kb = 0; kb < KB; ++kb) s += part[(size_t)kb*stride + idx];
  int orow = ((r >> rpgshift) * opg) + (r & ((1 << rpgshift) - 1));
  out[((size_t)orow << njshift) + j] = s;
}

// reduce batched Wv partials -> xs[b][t+1] (+bv). KB=16, R=224. grid 896.
__global__ __launch_bounds__(256) void mv2xs(
    const float* __restrict__ part, const float* __restrict__ bv, float* __restrict__ xs)
{
  int idx = blockIdx.x*256 + threadIdx.x;
  int r = idx >> 10, j = idx & 1023;
  int t = r >> 5, b = r & 31;
  const size_t stride = (size_t)224*1024;
  float s = bv[j];
#pragma unroll
  for (int kb = 0; kb < 16; ++kb) s += part[(size_t)kb*stride + idx];
  xs[(((size_t)b*Tn) + t + 1)*1024 + j] = s;
}

// ---------------- stage-2 kernels (R13 variants) ----------------

__global__ __launch_bounds__(512) void scores2_kernel(
    const float* __restrict__ hidden, const float* __restrict__ xk2, float* __restrict__ sc)
{
  int b = blockIdx.y, p = blockIdx.x;
  int lane = threadIdx.x & 63, w = threadIdx.x >> 6;
  int t0 = (w & 3) * 2, rh = w >> 2;
  const float4* qa = (const float4*)(xk2 + ((size_t)b*Tn + t0  )*Hn) + lane;
  const float4* qb = (const float4*)(xk2 + ((size_t)b*Tn + t0+1)*Hn) + lane;
  float4 a0=qa[0], a1=qa[64], a2=qa[128], a3=qa[192];
  float4 c0=qb[0], c1=qb[64], c2=qb[128], c3=qb[192];
#pragma unroll 2
  for (int r = 0; r < 8; ++r){
    int s = p*16 + rh*8 + r;
    const float4* row = (const float4*)(hidden + ((size_t)s*Bn + b)*Hn) + lane;
    float4 v0=row[0], v1=row[64], v2=row[128], v3=row[192];
    float d0 = wsum(dot16(a0,a1,a2,a3, v0,v1,v2,v3));
    float d1 = wsum(dot16(c0,c1,c2,c3, v0,v1,v2,v3));
    if (lane == 0){
      sc[((size_t)b*Tn + t0  )*Sn + s] = d0;
      sc[((size_t)b*Tn + t0+1)*Sn + s] = d1;
    }
  }
}

__global__ __launch_bounds__(512) void softmax512(float* __restrict__ sc){
  int row = blockIdx.x, tid = threadIdx.x, lane = tid & 63, w = tid >> 6;
  float v = sc[(size_t)row*Sn + tid];
  float mx = v;
#pragma unroll
  for (int off = 32; off; off >>= 1) mx = fmaxf(mx, __shfl_xor(mx, off));
  __shared__ float sm[8], ss[8];
  if (lane == 0) sm[w] = mx;
  __syncthreads();
  mx = sm[0];
#pragma unroll
  for (int i = 1; i < 8; ++i) mx = fmaxf(mx, sm[i]);
  float e = __expf(v - mx);
  float s = e;
#pragma unroll
  for (int off = 32; off; off >>= 1) s += __shfl_xor(s, off);
  if (lane == 0) ss[w] = s;
  __syncthreads();
  float tot = 0.f;
#pragma unroll
  for (int i = 0; i < 8; ++i) tot += ss[i];
  sc[(size_t)row*Sn + tid] = e / tot;
}

__global__ __launch_bounds__(512) void ctx2p(
    const float* __restrict__ hidden, const float* __restrict__ attn, float* __restrict__ part)
{
  int hc = blockIdx.x, sc = blockIdx.y, b = blockIdx.z;
  int tid = threadIdx.x, hloc = tid & 127, tg = tid >> 7;
  __shared__ float al[Tn*128];
  for (int idx = tid; idx < Tn*128; idx += 512){
    int t = idx >> 7, si = idx & 127;
    al[idx] = attn[((size_t)b*Tn + t)*Sn + sc*128 + si];
  }
  __syncthreads();
  int h = hc*128 + hloc, t0 = tg*2;
  float acc0 = 0.f, acc1 = 0.f;
#pragma unroll 4
  for (int si = 0; si < 128; ++si){
    int s = sc*128 + si;
    float v = hidden[((size_t)s*Bn + b)*Hn + h];
    acc0 = fmaf(al[t0*128 + si],     v, acc0);
    acc1 = fmaf(al[(t0+1)*128 + si], v, acc1);
  }
  part[(((size_t)sc*Bn + b)*Tn + t0  )*Hn + h] = acc0;
  part[(((size_t)sc*Bn + b)*Tn + t0+1)*Hn + h] = acc1;
}

__global__ __launch_bounds__(256) void ctx2r(const float* __restrict__ part, float* __restrict__ out){
  int idx = blockIdx.x*256 + threadIdx.x;
  out[idx] = part[idx] + part[262144 + idx] + part[524288 + idx] + part[786432 + idx];
}

// ---------------- LSTM: fused partial-reduce + pointwise ----------------
__global__ __launch_bounds__(256) void lstm_fused(
    const float* __restrict__ part, const float* __restrict__ b_ih,
    const float* __restrict__ b_hh, float* __restrict__ fq)
{
  int idx = blockIdx.x*256 + threadIdx.x;
  int b = idx >> 10, h = idx & 1023;
  const size_t stride = (size_t)32*Gn;
  float gi = b_ih[h] + b_hh[h];
  float gg = b_ih[2048+h] + b_hh[2048+h];
  float go = b_ih[3072+h] + b_hh[3072+h];
  for (int kb = 0; kb < 16; ++kb){
    const float* pp = part + (size_t)kb*stride + (size_t)b*Gn;
    gi += pp[h]; gg += pp[2048+h]; go += pp[3072+h];
  }
  float si = 1.f/(1.f + __expf(-gi));
  float so = 1.f/(1.f + __expf(-go));
  float c  = si * tanhf(gg);
  fq[((size_t)b*(Tn+1) + Tn)*Hn + h] = so * tanhf(c);
}

// ---------------- host ----------------

extern "C" void kernel_launch(void* const* d_in, const int* in_sizes, int n_in,
                              void* d_out, int out_size, void* d_ws, size_t ws_size,
                              hipStream_t stream) {
  const float* hidden = (const float*)d_in[0];
  const float* nums   = (const float*)d_in[1];
  const float* pq     = (const float*)d_in[2];
  const float* Wk     = (const float*)d_in[3];
  const float* Wv     = (const float*)d_in[5];
  const float* bv     = (const float*)d_in[6];
  const float* Wk2    = (const float*)d_in[7];
  const float* Wv2    = (const float*)d_in[9];
  const float* bv2    = (const float*)d_in[10];
  const float* W_ih   = (const float*)d_in[11];
  const float* b_ih   = (const float*)d_in[13];
  const float* b_hh   = (const float*)d_in[14];

  float* out = (float*)d_out;
  float* fq  = out;                                   // (B, T+1, H)
  float* uh  = out + (size_t)Bn*(Tn+1)*Hn;            // (S+T, B, H)
  float* un  = uh + (size_t)(Sn+Tn)*Bn*Hn;            // (B, N+T, H)

  // ws layout (floats); high-water 11,705,088 floats = 46.8 MB (<56 MB proven)
  float* ws    = (float*)d_ws;
  float* xs    = ws;                 // 262144
  float* ctxp  = ws + 262144;        // 524288 (B*16*H)
  float* mlp   = ws + 1310720;       // 1024
  float* xk2   = ws + 1345536;       // 262144
  float* sc2   = ws + 1607680;       // 131072
  float* ctx2v = ws + 1738752;       // 262144
  float* partX = ws + 2000896;       // 524288
  float* partK = ws + 2525184;       // 524288
  float* WkT   = ws + 3049472;       // 1048576
  float* Wk2T  = ws + 4098048;       // 1048576
  float* WvT   = ws + 5146624;       // 1048576
  float* Dcomb = ws + 6195200;       // 1048576
  float* ctxall= ws + 7243776;       // 229376 (7*32*1024)
  float* dk    = ws + 7473152;       // 1024
  float* Dparts= ws + 7474176;       // 4194304 (split-K partials)
  float* xkq   = ws + 11668480;      // 32768 (current q per b)
  unsigned* cnt= (unsigned*)(ws + 11701248); // 7*32*16 uints = 3584
  float* c2part= partX;              // ctx2 partials (spans partX+partK, disjoint lifetime)
  float* partL = WkT;                // LSTM partials (WkT/Wk2T dead by then; rewritten each call)

  transprep<<<dim3(32,32,4), 256, 0, stream>>>(Wk, Wk2, Wv, WkT, Wk2T, WvT,
      (const float4*)nums, (const float4*)pq, (float4*)un, (float4*)xs);
  mv1<<<dim3(8,4,32), 256, 0, stream>>>(WkT, Hn, WvT, Dparts, Hn, 4);
  dred<<<4352, 256, 0, stream>>>(Dparts, Dcomb, bv, WkT, dk);
  // xk0 = Wk^T problem_q
  mv1<<<dim3(8,16,1), 256, 0, stream>>>(pq, Hn, WkT, partK, Hn, 1);
  mv2<<<128, 256, 0, stream>>>(partK, 32, 10, 16, nullptr, nullptr, xkq, 0, 1);
  zcnt<<<1, 224, 0, stream>>>(cnt);

  // gen loop: 7 fused attend+combine+qslice kernels (per-b 16-block barrier)
  for (int t = 1; t < Tn; ++t){
    float* ctxt = ctxall + (size_t)(t-1)*Bn*Hn;
    unsigned* cs = cnt + (size_t)(t-1)*32*16;
    if (t == 1)
      attend11<1,0><<<512, 512, 0, stream>>>(hidden, xkq, dk, Dcomb, ctxp, mlp, xkq, ctxt, cs, uh);
    else if (t < Tn-1)
      attend11<0,0><<<512, 512, 0, stream>>>(hidden, xkq, dk, Dcomb, ctxp, mlp, xkq, ctxt, cs, uh);
    else
      attend11<0,1><<<512, 512, 0, stream>>>(hidden, xkq, dk, Dcomb, ctxp, mlp, xkq, ctxt, cs, uh);
  }

  // xs[:,1..7,:] = ctxall @ Wv^T + bv  (batched; KB=16)
  mv1<<<dim3(8,16,7), 256, 0, stream>>>(ctxall, Hn, Wv, Dparts, Hn, 1);
  mv2xs<<<896, 256, 0, stream>>>(Dparts, bv, xs);

  // stage 2
  mv1<<<dim3(8,16,8), 256, 0, stream>>>(xs, Hn, Wk2T, Dparts, Hn, 1);
  mv2<<<1024, 256, 0, stream>>>(Dparts, 256, 10, 16, nullptr, nullptr, xk2, 0, 1);
  scores2_kernel<<<dim3(32, Bn), 512, 0, stream>>>(hidden, xk2, sc2);
  softmax512<<<Bn*Tn, 512, 0, stream>>>(sc2);
  ctx2p<<<dim3(8, 4, Bn), 512, 0, stream>>>(hidden, sc2, c2part);
  ctx2r<<<1024, 256, 0, stream>>>(c2part, ctx2v);
  mv1<<<dim3(8,16,8), 256, 0, stream>>>(ctx2v, Hn, Wv2, Dparts, Hn, 1);
  mv2<<<1024, 256, 0, stream>>>(Dparts, 256, 10, 16, bv2, nullptr, fq, 3, Tn+1);

  // LSTM step 1 (partials overlay WkT/Wk2T -- dead by now)
  mv1<<<dim3(32,16,1), 256, 0, stream>>>(fq, (Tn+1)*Hn, W_ih, partL, Gn, 1);
  lstm_fused<<<128, 256, 0, stream>>>(partL, b_ih, b_hh, fq);

  finalize_xs<<<dim3(Tn, Bn), 256, 0, stream>>>((const float4*)xs, (float4*)uh, (float4*)un);
}

// Round 18
// 336.218 us; speedup vs baseline: 8.3121x; 1.3042x over previous
//
#include <hip/hip_runtime.h>
#include <math.h>

#define Bn 32
#define Sn 512
#define Hn 1024
#define Tn 8
#define Nn 16
#define Gn 4096

__device__ __forceinline__ float wsum(float v){
#pragma unroll
  for (int off = 32; off; off >>= 1) v += __shfl_xor(v, off);
  return v;
}

__device__ __forceinline__ float dot16(float4 a0, float4 a1, float4 a2, float4 a3,
                                       float4 v0, float4 v1, float4 v2, float4 v3){
  float d = a0.x*v0.x + a0.y*v0.y + a0.z*v0.z + a0.w*v0.w;
  d += a1.x*v1.x + a1.y*v1.y + a1.z*v1.z + a1.w*v1.w;
  d += a2.x*v2.x + a2.y*v2.y + a2.z*v2.z + a2.w*v2.w;
  d += a3.x*v3.x + a3.y*v3.y + a3.z*v3.z + a3.w*v3.w;
  return d;
}

// ---------------- prep: 3 transposes + nums/pq copies in ONE launch ----------
__global__ __launch_bounds__(256) void transprep(
    const float* __restrict__ Wk, const float* __restrict__ Wk2, const float* __restrict__ Wv,
    float* __restrict__ WkT, float* __restrict__ Wk2T, float* __restrict__ WvT,
    const float4* __restrict__ nums, const float4* __restrict__ pq,
    float4* __restrict__ un, float4* __restrict__ xs){
  if (blockIdx.z == 3){
    int n = blockIdx.x, b = blockIdx.y;
    if (n < Nn) un[((size_t)b*(Nn+Tn) + n)*256 + threadIdx.x] = nums[((size_t)b*Nn + n)*256 + threadIdx.x];
    else if (n == Nn) xs[((size_t)b*Tn)*256 + threadIdx.x] = pq[(size_t)b*256 + threadIdx.x];
    return;
  }
  __shared__ float tile[32][33];
  const float* in  = (blockIdx.z == 0) ? Wk  : (blockIdx.z == 1) ? Wk2  : Wv;
  float*       outp= (blockIdx.z == 0) ? WkT : (blockIdx.z == 1) ? Wk2T : WvT;
  int tx = threadIdx.x & 31, ty = threadIdx.x >> 5;
  int c0 = blockIdx.x * 32, r0 = blockIdx.y * 32;
#pragma unroll
  for (int k = 0; k < 4; ++k)
    tile[ty + 8*k][tx] = in[(size_t)(r0 + ty + 8*k) * Hn + c0 + tx];
  __syncthreads();
#pragma unroll
  for (int k = 0; k < 4; ++k)
    outp[(size_t)(c0 + ty + 8*k) * Hn + r0 + tx] = tile[tx][ty + 8*k];
}

__global__ __launch_bounds__(256) void finalize_xs(const float4* __restrict__ xs, float4* __restrict__ uh, float4* __restrict__ un){
  int t = blockIdx.x, b = blockIdx.y;
  float4 v = xs[((size_t)b*Tn + t)*256 + threadIdx.x];
  uh[(((size_t)(Sn + t))*Bn + b)*256 + threadIdx.x] = v;
  un[((size_t)b*(Nn+Tn) + Nn + t)*256 + threadIdx.x] = v;
}

// ---------------- dred: Dcomb split-K reduce + dkv fused. grid 4352 ----------
__global__ __launch_bounds__(256) void dred(
    const float* __restrict__ Dparts, float* __restrict__ Dcomb,
    const float* __restrict__ bv, const float* __restrict__ WkT, float* __restrict__ dk)
{
  if (blockIdx.x < 4096){
    int idx = blockIdx.x*256 + threadIdx.x;
    const size_t stride = (size_t)1024*1024;
    float s = Dparts[idx] + Dparts[stride + idx] + Dparts[2*stride + idx] + Dparts[3*stride + idx];
    Dcomb[idx] = s;
  } else {
    int lane = threadIdx.x & 63, w = threadIdx.x >> 6;
    int j = (blockIdx.x - 4096)*4 + w;
    const float4* rp = (const float4*)(WkT + (size_t)j*Hn) + lane;
    const float4* bp = (const float4*)bv + lane;
    float4 v0=rp[0], v1=rp[64], v2=rp[128], v3=rp[192];
    float4 b0=bp[0], b1=bp[64], b2=bp[128], b3=bp[192];
    float d = wsum(dot16(b0,b1,b2,b3, v0,v1,v2,v3));
    if (lane == 0) dk[j] = d;
  }
}

// ---------------- attention (gen loop): q-reduce folded in (R13, proven) ----
template<int FIRST>
__global__ __launch_bounds__(512, 4) void attend10(
    const float* __restrict__ hidden, const float* __restrict__ partq,
    const float* __restrict__ dk,
    float* __restrict__ ctxp, float* __restrict__ mlp, float* __restrict__ uh)
{
  const int b = blockIdx.y, p = blockIdx.x;
  const int tid = threadIdx.x, lane = tid & 63, w = tid >> 6;
  __shared__ float xq[1024];
  __shared__ float sM[8], sL[8];
  __shared__ float sacc[8*1024];

  const int s0 = p*32 + w*4;
  size_t ro[4];
#pragma unroll
  for (int i = 0; i < 4; ++i) ro[i] = ((size_t)(s0+i)*Bn + b)*Hn;
  float4 u[4][4];
#pragma unroll
  for (int i = 0; i < 4; ++i){
    const float4* rp = (const float4*)(hidden + ro[i]) + lane;
    u[i][0]=rp[0]; u[i][1]=rp[64]; u[i][2]=rp[128]; u[i][3]=rp[192];
  }
#pragma unroll
  for (int h0 = 0; h0 < 1024; h0 += 512){
    int c = h0 + tid;
    float s = dk ? dk[c] : 0.f;
#pragma unroll
    for (int i = 0; i < 16; ++i) s += partq[((size_t)(i*Bn + b))*1024 + c];
    xq[c] = s;
  }
  if (FIRST){
#pragma unroll
    for (int i = 0; i < 4; ++i){
      float4* wp = (float4*)(uh + ro[i]) + lane;
      wp[0]=u[i][0]; wp[64]=u[i][1]; wp[128]=u[i][2]; wp[192]=u[i][3];
    }
  }
  __syncthreads();
  const float4* xp = (const float4*)xq + lane;
  float4 q0 = xp[0], q1 = xp[64], q2 = xp[128], q3 = xp[192];

  float d[4];
#pragma unroll
  for (int i = 0; i < 4; ++i) d[i] = dot16(q0,q1,q2,q3, u[i][0],u[i][1],u[i][2],u[i][3]);
#pragma unroll
  for (int off = 32; off; off >>= 1){
#pragma unroll
    for (int i = 0; i < 4; ++i) d[i] += __shfl_xor(d[i], off);
  }
  float mw = fmaxf(fmaxf(d[0], d[1]), fmaxf(d[2], d[3]));
  sM[w] = mw;
  __syncthreads();
  float M = sM[0];
#pragma unroll
  for (int i = 1; i < 8; ++i) M = fmaxf(M, sM[i]);
  float wi[4], lw = 0.f;
#pragma unroll
  for (int i = 0; i < 4; ++i){ wi[i] = __expf(d[i] - M); lw += wi[i]; }
  float4 a0, a1, a2, a3;
  a0 = make_float4(wi[0]*u[0][0].x, wi[0]*u[0][0].y, wi[0]*u[0][0].z, wi[0]*u[0][0].w);
  a1 = make_float4(wi[0]*u[0][1].x, wi[0]*u[0][1].y, wi[0]*u[0][1].z, wi[0]*u[0][1].w);
  a2 = make_float4(wi[0]*u[0][2].x, wi[0]*u[0][2].y, wi[0]*u[0][2].z, wi[0]*u[0][2].w);
  a3 = make_float4(wi[0]*u[0][3].x, wi[0]*u[0][3].y, wi[0]*u[0][3].z, wi[0]*u[0][3].w);
#pragma unroll
  for (int i = 1; i < 4; ++i){
    a0.x = fmaf(wi[i], u[i][0].x, a0.x); a0.y = fmaf(wi[i], u[i][0].y, a0.y);
    a0.z = fmaf(wi[i], u[i][0].z, a0.z); a0.w = fmaf(wi[i], u[i][0].w, a0.w);
    a1.x = fmaf(wi[i], u[i][1].x, a1.x); a1.y = fmaf(wi[i], u[i][1].y, a1.y);
    a1.z = fmaf(wi[i], u[i][1].z, a1.z); a1.w = fmaf(wi[i], u[i][1].w, a1.w);
    a2.x = fmaf(wi[i], u[i][2].x, a2.x); a2.y = fmaf(wi[i], u[i][2].y, a2.y);
    a2.z = fmaf(wi[i], u[i][2].z, a2.z); a2.w = fmaf(wi[i], u[i][2].w, a2.w);
    a3.x = fmaf(wi[i], u[i][3].x, a3.x); a3.y = fmaf(wi[i], u[i][3].y, a3.y);
    a3.z = fmaf(wi[i], u[i][3].z, a3.z); a3.w = fmaf(wi[i], u[i][3].w, a3.w);
  }
  {
    int sl0 = (lane*4 + 0) ^ (lane & 7);
    int sl1 = (lane*4 + 1) ^ (lane & 7);
    int sl2 = (lane*4 + 2) ^ (lane & 7);
    int sl3 = (lane*4 + 3) ^ (lane & 7);
    *(float4*)(sacc + w*1024 + sl0*4) = a0;
    *(float4*)(sacc + w*1024 + sl1*4) = a1;
    *(float4*)(sacc + w*1024 + sl2*4) = a2;
    *(float4*)(sacc + w*1024 + sl3*4) = a3;
  }
  if (lane == 0) sL[w] = lw;
  __syncthreads();
#pragma unroll
  for (int h0 = 0; h0 < 1024; h0 += 512){
    int c = h0 + tid;
    int k = c >> 8, l = (c >> 2) & 63, j = c & 3;
    int fo = ((((l << 2) + k) ^ (l & 7)) << 2) + j;
    float s = 0.f;
#pragma unroll
    for (int i = 0; i < 8; ++i) s += sacc[i*1024 + fo];
    ctxp[((size_t)b*16 + p)*1024 + c] = s;
  }
  if (tid == 0){
    float L = 0.f;
#pragma unroll
    for (int i = 0; i < 8; ++i) L += sL[i];
    mlp[((size_t)b*16 + p)*2]     = M;
    mlp[((size_t)b*16 + p)*2 + 1] = L;
  }
}

// ---------------- genw: fused combine + D matvec (R13, proven) ----------------
template<int FULL>
__global__ __launch_bounds__(256) void genw(
    const float* __restrict__ ctxp, const float* __restrict__ mlp,
    const float* __restrict__ D, float* __restrict__ part, float* __restrict__ ctxout)
{
  __shared__ float wt[64*128];
  __shared__ float xl[64*32];
  const int t  = threadIdx.x;
  const int j0 = blockIdx.x * 128;
  const int kb = blockIdx.y;
  const int k0 = kb*64;
  const int tj = t & 31, tr = t >> 5;

  if (FULL){
    int j = t >> 1;
    int kqb = (t & 1) * 8;
    const float* Mrow = D + (size_t)(j0 + j)*1024 + k0;
#pragma unroll
    for (int c = 0; c < 8; ++c){
      float4 v = *(const float4*)(Mrow + (kqb + c)*4);
      int kk = (kqb + c)*4;
      wt[(kk+0)*128 + j] = v.x;
      wt[(kk+1)*128 + j] = v.y;
      wt[(kk+2)*128 + j] = v.z;
      wt[(kk+3)*128 + j] = v.w;
    }
  }
  {
    int b = t >> 3, kk = (t & 7)*8;
    float mx = -1e30f;
#pragma unroll
    for (int i = 0; i < 16; ++i) mx = fmaxf(mx, mlp[((size_t)b*16 + i)*2]);
    float L = 0.f;
    float a8[8] = {0.f,0.f,0.f,0.f,0.f,0.f,0.f,0.f};
#pragma unroll 4
    for (int i = 0; i < 16; ++i){
      float m = mlp[((size_t)b*16 + i)*2];
      float l = mlp[((size_t)b*16 + i)*2 + 1];
      float we = __expf(m - mx);
      L = fmaf(l, we, L);
      const float* cp = ctxp + ((size_t)b*16 + i)*1024 + k0 + kk;
      float4 u0 = *(const float4*)cp;
      float4 u1 = *(const float4*)(cp + 4);
      a8[0] = fmaf(we, u0.x, a8[0]); a8[1] = fmaf(we, u0.y, a8[1]);
      a8[2] = fmaf(we, u0.z, a8[2]); a8[3] = fmaf(we, u0.w, a8[3]);
      a8[4] = fmaf(we, u1.x, a8[4]); a8[5] = fmaf(we, u1.y, a8[5]);
      a8[6] = fmaf(we, u1.z, a8[6]); a8[7] = fmaf(we, u1.w, a8[7]);
    }
    float inv = 1.f / L;
#pragma unroll
    for (int q = 0; q < 8; ++q){
      float c = a8[q]*inv;
      if (FULL) xl[(kk + q)*32 + b] = c;
      if (!FULL || blockIdx.x == 0) ctxout[(size_t)b*1024 + k0 + kk + q] = c;
    }
  }
  if (!FULL) return;
  __syncthreads();
  float acc[4][4] = {{0.f,0.f,0.f,0.f},{0.f,0.f,0.f,0.f},{0.f,0.f,0.f,0.f},{0.f,0.f,0.f,0.f}};
#pragma unroll 4
  for (int k = 0; k < 64; ++k){
    float4 w4 = *(const float4*)(wt + k*128 + tj*4);
    float4 x4 = *(const float4*)(xl + k*32  + tr*4);
    acc[0][0] = fmaf(x4.x, w4.x, acc[0][0]);
    acc[0][1] = fmaf(x4.x, w4.y, acc[0][1]);
    acc[0][2] = fmaf(x4.x, w4.z, acc[0][2]);
    acc[0][3] = fmaf(x4.x, w4.w, acc[0][3]);
    acc[1][0] = fmaf(x4.y, w4.x, acc[1][0]);
    acc[1][1] = fmaf(x4.y, w4.y, acc[1][1]);
    acc[1][2] = fmaf(x4.y, w4.z, acc[1][2]);
    acc[1][3] = fmaf(x4.y, w4.w, acc[1][3]);
    acc[2][0] = fmaf(x4.z, w4.x, acc[2][0]);
    acc[2][1] = fmaf(x4.z, w4.y, acc[2][1]);
    acc[2][2] = fmaf(x4.z, w4.z, acc[2][2]);
    acc[2][3] = fmaf(x4.z, w4.w, acc[2][3]);
    acc[3][0] = fmaf(x4.w, w4.x, acc[3][0]);
    acc[3][1] = fmaf(x4.w, w4.y, acc[3][1]);
    acc[3][2] = fmaf(x4.w, w4.z, acc[3][2]);
    acc[3][3] = fmaf(x4.w, w4.w, acc[3][3]);
  }
  const size_t base = ((size_t)kb*32 + tr*4)*1024 + j0 + tj*4;
#pragma unroll
  for (int i = 0; i < 4; ++i)
    *(float4*)(part + base + (size_t)i*1024) = make_float4(acc[i][0], acc[i][1], acc[i][2], acc[i][3]);
}

// ---------------- split-K register-tiled matvec ----------------
__global__ __launch_bounds__(256) void mv1(
    const float* __restrict__ X, int xstride,
    const float* __restrict__ M, float* __restrict__ part,
    int nj, int ktiles)
{
  __shared__ float wt[64*128];
  __shared__ float xl[64*32];
  const int t  = threadIdx.x;
  const int j0 = blockIdx.x * 128;
  const int kb = blockIdx.y;
  const int r0 = blockIdx.z * 32;
  const int R  = gridDim.z * 32;
  const int tj = t & 31, tr = t >> 5;
  float acc[4][4] = {{0.f,0.f,0.f,0.f},{0.f,0.f,0.f,0.f},{0.f,0.f,0.f,0.f},{0.f,0.f,0.f,0.f}};

  for (int kt = 0; kt < ktiles; ++kt){
    const int k0 = (kb*ktiles + kt)*64;
    __syncthreads();
    {
      int j = t >> 1;
      int kqb = (t & 1) * 8;
      const float* Mrow = M + (size_t)(j0 + j)*1024 + k0;
#pragma unroll
      for (int c = 0; c < 8; ++c){
        float4 v = *(const float4*)(Mrow + (kqb + c)*4);
        int kk = (kqb + c)*4;
        wt[(kk+0)*128 + j] = v.x;
        wt[(kk+1)*128 + j] = v.y;
        wt[(kk+2)*128 + j] = v.z;
        wt[(kk+3)*128 + j] = v.w;
      }
      int r = t >> 3;
      int kq0 = t & 7;
#pragma unroll
      for (int c = 0; c < 2; ++c){
        int kk = (kq0 + c*8)*4;
        float4 v = *(const float4*)(X + (size_t)(r0 + r)*xstride + k0 + kk);
        xl[(kk+0)*32 + r] = v.x;
        xl[(kk+1)*32 + r] = v.y;
        xl[(kk+2)*32 + r] = v.z;
        xl[(kk+3)*32 + r] = v.w;
      }
    }
    __syncthreads();
#pragma unroll 4
    for (int k = 0; k < 64; ++k){
      float4 w4 = *(const float4*)(wt + k*128 + tj*4);
      float4 x4 = *(const float4*)(xl + k*32  + tr*4);
      acc[0][0] = fmaf(x4.x, w4.x, acc[0][0]);
      acc[0][1] = fmaf(x4.x, w4.y, acc[0][1]);
      acc[0][2] = fmaf(x4.x, w4.z, acc[0][2]);
      acc[0][3] = fmaf(x4.x, w4.w, acc[0][3]);
      acc[1][0] = fmaf(x4.y, w4.x, acc[1][0]);
      acc[1][1] = fmaf(x4.y, w4.y, acc[1][1]);
      acc[1][2] = fmaf(x4.y, w4.z, acc[1][2]);
      acc[1][3] = fmaf(x4.y, w4.w, acc[1][3]);
      acc[2][0] = fmaf(x4.z, w4.x, acc[2][0]);
      acc[2][1] = fmaf(x4.z, w4.y, acc[2][1]);
      acc[2][2] = fmaf(x4.z, w4.z, acc[2][2]);
      acc[2][3] = fmaf(x4.z, w4.w, acc[2][3]);
      acc[3][0] = fmaf(x4.w, w4.x, acc[3][0]);
      acc[3][1] = fmaf(x4.w, w4.y, acc[3][1]);
      acc[3][2] = fmaf(x4.w, w4.z, acc[3][2]);
      acc[3][3] = fmaf(x4.w, w4.w, acc[3][3]);
    }
  }
  const size_t base = ((size_t)kb*R + r0 + tr*4)*nj + j0 + tj*4;
#pragma unroll
  for (int i = 0; i < 4; ++i)
    *(float4*)(part + base + (size_t)i*nj) = make_float4(acc[i][0], acc[i][1], acc[i][2], acc[i][3]);
}

__global__ __launch_bounds__(256) void mv2(
    const float* __restrict__ part, int R, int njshift, int KB,
    const float* __restrict__ b1, const float* __restrict__ b2,
    float* __restrict__ out, int rpgshift, int opg)
{
  int idx = blockIdx.x*256 + threadIdx.x;
  int nj = 1 << njshift;
  int r = idx >> njshift, j = idx & (nj - 1);
  float s = 0.f;
  if (b1) s += b1[j];
  if (b2) s += b2[j];
  size_t stride = (size_t)R << njshift;
  for (int kb = 0; kb < KB; ++kb) s += part[(size_t)kb*stride + idx];
  int orow = ((r >> rpgshift) * opg) + (r & ((1 << rpgshift) - 1));
  out[((size_t)orow << njshift) + j] = s;
}

// reduce batched Wv partials -> xs[b][t+1] (+bv). KB=16, R=224. grid 896.
__global__ __launch_bounds__(256) void mv2xs(
    const float* __restrict__ part, const float* __restrict__ bv, float* __restrict__ xs)
{
  int idx = blockIdx.x*256 + threadIdx.x;
  int r = idx >> 10, j = idx & 1023;
  int t = r >> 5, b = r & 31;
  const size_t stride = (size_t)224*1024;
  float s = bv[j];
#pragma unroll
  for (int kb = 0; kb < 16; ++kb) s += part[(size_t)kb*stride + idx];
  xs[(((size_t)b*Tn) + t + 1)*1024 + j] = s;
}

// ---------------- stage-2 kernels (R13 variants, proven) ----------------

__global__ __launch_bounds__(512) void scores2_kernel(
    const float* __restrict__ hidden, const float* __restrict__ xk2, float* __restrict__ sc)
{
  int b = blockIdx.y, p = blockIdx.x;
  int lane = threadIdx.x & 63, w = threadIdx.x >> 6;
  int t0 = (w & 3) * 2, rh = w >> 2;
  const float4* qa = (const float4*)(xk2 + ((size_t)b*Tn + t0  )*Hn) + lane;
  const float4* qb = (const float4*)(xk2 + ((size_t)b*Tn + t0+1)*Hn) + lane;
  float4 a0=qa[0], a1=qa[64], a2=qa[128], a3=qa[192];
  float4 c0=qb[0], c1=qb[64], c2=qb[128], c3=qb[192];
#pragma unroll 2
  for (int r = 0; r < 8; ++r){
    int s = p*16 + rh*8 + r;
    const float4* row = (const float4*)(hidden + ((size_t)s*Bn + b)*Hn) + lane;
    float4 v0=row[0], v1=row[64], v2=row[128], v3=row[192];
    float d0 = wsum(dot16(a0,a1,a2,a3, v0,v1,v2,v3));
    float d1 = wsum(dot16(c0,c1,c2,c3, v0,v1,v2,v3));
    if (lane == 0){
      sc[((size_t)b*Tn + t0  )*Sn + s] = d0;
      sc[((size_t)b*Tn + t0+1)*Sn + s] = d1;
    }
  }
}

__global__ __launch_bounds__(512) void softmax512(float* __restrict__ sc){
  int row = blockIdx.x, tid = threadIdx.x, lane = tid & 63, w = tid >> 6;
  float v = sc[(size_t)row*Sn + tid];
  float mx = v;
#pragma unroll
  for (int off = 32; off; off >>= 1) mx = fmaxf(mx, __shfl_xor(mx, off));
  __shared__ float sm[8], ss[8];
  if (lane == 0) sm[w] = mx;
  __syncthreads();
  mx = sm[0];
#pragma unroll
  for (int i = 1; i < 8; ++i) mx = fmaxf(mx, sm[i]);
  float e = __expf(v - mx);
  float s = e;
#pragma unroll
  for (int off = 32; off; off >>= 1) s += __shfl_xor(s, off);
  if (lane == 0) ss[w] = s;
  __syncthreads();
  float tot = 0.f;
#pragma unroll
  for (int i = 0; i < 8; ++i) tot += ss[i];
  sc[(size_t)row*Sn + tid] = e / tot;
}

__global__ __launch_bounds__(512) void ctx2p(
    const float* __restrict__ hidden, const float* __restrict__ attn, float* __restrict__ part)
{
  int hc = blockIdx.x, sc = blockIdx.y, b = blockIdx.z;
  int tid = threadIdx.x, hloc = tid & 127, tg = tid >> 7;
  __shared__ float al[Tn*128];
  for (int idx = tid; idx < Tn*128; idx += 512){
    int t = idx >> 7, si = idx & 127;
    al[idx] = attn[((size_t)b*Tn + t)*Sn + sc*128 + si];
  }
  __syncthreads();
  int h = hc*128 + hloc, t0 = tg*2;
  float acc0 = 0.f, acc1 = 0.f;
#pragma unroll 4
  for (int si = 0; si < 128; ++si){
    int s = sc*128 + si;
    float v = hidden[((size_t)s*Bn + b)*Hn + h];
    acc0 = fmaf(al[t0*128 + si],     v, acc0);
    acc1 = fmaf(al[(t0+1)*128 + si], v, acc1);
  }
  part[(((size_t)sc*Bn + b)*Tn + t0  )*Hn + h] = acc0;
  part[(((size_t)sc*Bn + b)*Tn + t0+1)*Hn + h] = acc1;
}

__global__ __launch_bounds__(256) void ctx2r(const float* __restrict__ part, float* __restrict__ out){
  int idx = blockIdx.x*256 + threadIdx.x;
  out[idx] = part[idx] + part[262144 + idx] + part[524288 + idx] + part[786432 + idx];
}

// ---------------- LSTM: fused partial-reduce + pointwise ----------------
__global__ __launch_bounds__(256) void lstm_fused(
    const float* __restrict__ part, const float* __restrict__ b_ih,
    const float* __restrict__ b_hh, float* __restrict__ fq)
{
  int idx = blockIdx.x*256 + threadIdx.x;
  int b = idx >> 10, h = idx & 1023;
  const size_t stride = (size_t)32*Gn;
  float gi = b_ih[h] + b_hh[h];
  float gg = b_ih[2048+h] + b_hh[2048+h];
  float go = b_ih[3072+h] + b_hh[3072+h];
  for (int kb = 0; kb < 16; ++kb){
    const float* pp = part + (size_t)kb*stride + (size_t)b*Gn;
    gi += pp[h]; gg += pp[2048+h]; go += pp[3072+h];
  }
  float si = 1.f/(1.f + __expf(-gi));
  float so = 1.f/(1.f + __expf(-go));
  float c  = si * tanhf(gg);
  fq[((size_t)b*(Tn+1) + Tn)*Hn + h] = so * tanhf(c);
}

// ---------------- host ----------------

extern "C" void kernel_launch(void* const* d_in, const int* in_sizes, int n_in,
                              void* d_out, int out_size, void* d_ws, size_t ws_size,
                              hipStream_t stream) {
  const float* hidden = (const float*)d_in[0];
  const float* nums   = (const float*)d_in[1];
  const float* pq     = (const float*)d_in[2];
  const float* Wk     = (const float*)d_in[3];
  const float* Wv     = (const float*)d_in[5];
  const float* bv     = (const float*)d_in[6];
  const float* Wk2    = (const float*)d_in[7];
  const float* Wv2    = (const float*)d_in[9];
  const float* bv2    = (const float*)d_in[10];
  const float* W_ih   = (const float*)d_in[11];
  const float* b_ih   = (const float*)d_in[13];
  const float* b_hh   = (const float*)d_in[14];

  float* out = (float*)d_out;
  float* fq  = out;                                   // (B, T+1, H)
  float* uh  = out + (size_t)Bn*(Tn+1)*Hn;            // (S+T, B, H)
  float* un  = uh + (size_t)(Sn+Tn)*Bn*Hn;            // (B, N+T, H)

  // ws layout (floats); high-water 11,668,480 floats = 46.7 MB (<56 MB proven)
  float* ws    = (float*)d_ws;
  float* xs    = ws;                 // 262144
  float* ctxp  = ws + 262144;        // 524288 (B*16*H)
  float* mlp   = ws + 1310720;       // 1024
  float* xk2   = ws + 1345536;       // 262144
  float* sc2   = ws + 1607680;       // 131072
  float* ctx2v = ws + 1738752;       // 262144
  float* partX = ws + 2000896;       // 524288 (16*32*1024)
  float* partK = ws + 2525184;       // 524288
  float* WkT   = ws + 3049472;       // 1048576
  float* Wk2T  = ws + 4098048;       // 1048576
  float* WvT   = ws + 5146624;       // 1048576
  float* Dcomb = ws + 6195200;       // 1048576
  float* ctxall= ws + 7243776;       // 229376 (7*32*1024)
  float* dk    = ws + 7473152;       // 1024
  float* Dparts= ws + 7474176;       // 4194304 (split-K partials)
  float* c2part= partX;              // ctx2 partials (spans partX+partK, disjoint lifetime)
  float* partL = WkT;                // LSTM partials (WkT/Wk2T dead by then; rewritten each call)

  transprep<<<dim3(32,32,4), 256, 0, stream>>>(Wk, Wk2, Wv, WkT, Wk2T, WvT,
      (const float4*)nums, (const float4*)pq, (float4*)un, (float4*)xs);
  // one-time: D = Wk^T * Wv (split-K KB=4) + fused reduce/dkv
  mv1<<<dim3(8,4,32), 256, 0, stream>>>(WkT, Hn, WvT, Dparts, Hn, 4);
  dred<<<4352, 256, 0, stream>>>(Dparts, Dcomb, bv, WkT, dk);
  // xk0 partials = Wk^T problem_q (attend folds the reduce itself)
  mv1<<<dim3(8,16,1), 256, 0, stream>>>(pq, Hn, WkT, partK, Hn, 1);

  // gen loop (R13 structure: kernel-boundary sync is the cheapest barrier)
  for (int t = 1; t < Tn; ++t){
    if (t == 1) attend10<1><<<dim3(16,Bn), 512, 0, stream>>>(hidden, partK, nullptr, ctxp, mlp, uh);
    else        attend10<0><<<dim3(16,Bn), 512, 0, stream>>>(hidden, partX, dk, ctxp, mlp, uh);
    float* ctxt = ctxall + (size_t)(t-1)*Bn*Hn;
    if (t < Tn-1) genw<1><<<dim3(8,16), 256, 0, stream>>>(ctxp, mlp, Dcomb, partX, ctxt);
    else          genw<0><<<dim3(1,16), 256, 0, stream>>>(ctxp, mlp, Dcomb, partX, ctxt);
  }

  // xs[:,1..7,:] = ctxall @ Wv^T + bv  (batched; KB=16)
  mv1<<<dim3(8,16,7), 256, 0, stream>>>(ctxall, Hn, Wv, Dparts, Hn, 1);
  mv2xs<<<896, 256, 0, stream>>>(Dparts, bv, xs);

  // stage 2
  mv1<<<dim3(8,16,8), 256, 0, stream>>>(xs, Hn, Wk2T, Dparts, Hn, 1);
  mv2<<<1024, 256, 0, stream>>>(Dparts, 256, 10, 16, nullptr, nullptr, xk2, 0, 1);
  scores2_kernel<<<dim3(32, Bn), 512, 0, stream>>>(hidden, xk2, sc2);
  softmax512<<<Bn*Tn, 512, 0, stream>>>(sc2);
  ctx2p<<<dim3(8, 4, Bn), 512, 0, stream>>>(hidden, sc2, c2part);
  ctx2r<<<1024, 256, 0, stream>>>(c2part, ctx2v);
  mv1<<<dim3(8,16,8), 256, 0, stream>>>(ctx2v, Hn, Wv2, Dparts, Hn, 1);
  mv2<<<1024, 256, 0, stream>>>(Dparts, 256, 10, 16, bv2, nullptr, fq, 3, Tn+1);

  // LSTM step 1 (partials overlay WkT/Wk2T -- dead by now)
  mv1<<<dim3(32,16,1), 256, 0, stream>>>(fq, (Tn+1)*Hn, W_ih, partL, Gn, 1);
  lstm_fused<<<128, 256, 0, stream>>>(partL, b_ih, b_hh, fq);

  finalize_xs<<<dim3(Tn, Bn), 256, 0, stream>>>((const float4*)xs, (float4*)uh, (float4*)un);
}